// Round 5
// baseline (4427.423 us; speedup 1.0000x reference)
//
#include <hip/hip_runtime.h>
#include <cmath>

#define S 4096
#define HID 768
#define NH 12
#define DH 64
#define CHUNK 256
#define NC (S / CHUNK)
#define NG 16
#define FF 3072
#define NLAYER 12
#define QKV3 (3 * HID)
#define NEGV -1e9f

typedef _Float16 f16;
typedef __attribute__((ext_vector_type(2))) _Float16 f16x2;
typedef __attribute__((ext_vector_type(4))) _Float16 f16x4;
typedef __attribute__((ext_vector_type(8))) _Float16 f16x8;
typedef __attribute__((ext_vector_type(4))) float f32x4;

__device__ __forceinline__ void async16(f16* lds, const f16* g) {
  __builtin_amdgcn_global_load_lds((const __attribute__((address_space(1))) unsigned int*)g,
                                   (__attribute__((address_space(3))) unsigned int*)lds,
                                   16, 0, 0);
}

// ---------------- block reduction helpers (blockDim.x == 256) ----------------
__device__ __forceinline__ float block_reduce_sum(float v, float* red) {
  int t = threadIdx.x;
  red[t] = v; __syncthreads();
  for (int st = 128; st > 0; st >>= 1) {
    if (t < st) red[t] += red[t + st];
    __syncthreads();
  }
  float r = red[0]; __syncthreads();
  return r;
}
__device__ __forceinline__ float block_reduce_max(float v, float* red) {
  int t = threadIdx.x;
  red[t] = v; __syncthreads();
  for (int st = 128; st > 0; st >>= 1) {
    if (t < st) red[t] = fmaxf(red[t], red[t + st]);
    __syncthreads();
  }
  float r = red[0]; __syncthreads();
  return r;
}

// ---------------- gidx / gvalid (matches jax top_k semantics) ----------------
__global__ void gidx_kernel(const int* __restrict__ gmask, int* __restrict__ gidx,
                            float* __restrict__ gvalid) {
  if (threadIdx.x != 0 || blockIdx.x != 0) return;
  int cnt = 0;
  for (int s = 0; s < S && cnt < NG; s++)
    if (gmask[s] > 0) { gidx[cnt] = s; gvalid[cnt] = 1.f; cnt++; }
  for (int s = 0; s < S && cnt < NG; s++)
    if (gmask[s] == 0) { gidx[cnt] = s; gvalid[cnt] = 0.f; cnt++; }
}

// ---------------- embedding + LayerNorm (writes f32 + f16) ----------------
__global__ __launch_bounds__(256) void embed_ln_kernel(
    const int* __restrict__ ids, const float* __restrict__ tok,
    const float* __restrict__ pos, const float* __restrict__ g,
    const float* __restrict__ b, float* __restrict__ h, f16* __restrict__ h16) {
  int s = blockIdx.x, t = threadIdx.x;
  __shared__ float xs[HID];
  __shared__ float red[256];
  const float* tr = tok + (size_t)ids[s] * HID;
  const float* pr = pos + (size_t)s * HID;
  float ls = 0.f;
  for (int i = t; i < HID; i += 256) { float v = tr[i] + pr[i]; xs[i] = v; ls += v; }
  float mu = block_reduce_sum(ls, red) * (1.f / HID);
  float lv = 0.f;
  for (int i = t; i < HID; i += 256) { float d = xs[i] - mu; lv += d * d; }
  float var = block_reduce_sum(lv, red) * (1.f / HID);
  float inv = rsqrtf(var + 1e-5f);
  for (int i = t; i < HID; i += 256) {
    float o = (xs[i] - mu) * inv * g[i] + b[i];
    h[(size_t)s * HID + i] = o;
    h16[(size_t)s * HID + i] = (f16)o;
  }
}

// ---------------- residual add + LayerNorm (in-place on h, also f16) ----------------
__global__ __launch_bounds__(256) void add_ln_kernel(
    float* __restrict__ h, const float* __restrict__ x2,
    const float* __restrict__ g, const float* __restrict__ b, f16* __restrict__ h16) {
  int s = blockIdx.x, t = threadIdx.x;
  __shared__ float xs[HID];
  __shared__ float red[256];
  float ls = 0.f;
  for (int i = t; i < HID; i += 256) {
    float v = h[(size_t)s * HID + i] + x2[(size_t)s * HID + i];
    xs[i] = v; ls += v;
  }
  float mu = block_reduce_sum(ls, red) * (1.f / HID);
  float lv = 0.f;
  for (int i = t; i < HID; i += 256) { float d = xs[i] - mu; lv += d * d; }
  float var = block_reduce_sum(lv, red) * (1.f / HID);
  float inv = rsqrtf(var + 1e-5f);
  for (int i = t; i < HID; i += 256) {
    float o = (xs[i] - mu) * inv * g[i] + b[i];
    h[(size_t)s * HID + i] = o;
    h16[(size_t)s * HID + i] = (f16)o;
  }
}

// ------ weight transpose + f16 convert, ALL layers: W[l][K][N] f32 -> WT[l][N][K] f16
__global__ __launch_bounds__(256) void wt_kernel(const float* __restrict__ W,
                                                 f16* __restrict__ WT, int K, int N) {
  size_t lo = (size_t)blockIdx.z * K * N;
  const float* Wl = W + lo;
  f16* WTl = WT + lo;
  __shared__ float tile[32][33];
  int k0 = blockIdx.y * 32, n0 = blockIdx.x * 32;
  int t = threadIdx.x;
  int r = t >> 3, c = (t & 7) * 4;
  float4 v = *(const float4*)&Wl[(size_t)(k0 + r) * N + n0 + c];
  tile[r][c] = v.x; tile[r][c + 1] = v.y; tile[r][c + 2] = v.z; tile[r][c + 3] = v.w;
  __syncthreads();
  int n = t >> 3, kq = (t & 7) * 4;
  f16x4 o = {(f16)tile[kq][n], (f16)tile[kq + 1][n], (f16)tile[kq + 2][n], (f16)tile[kq + 3][n]};
  *(f16x4*)&WTl[(size_t)(n0 + n) * K + k0 + kq] = o;
}

// ---------------- fp16 MFMA GEMM 128x128: C = A @ BT^T + bias ----------------
#define GBK 64

template <int OMODE, bool GELU>  // OMODE 0: f32 out, 1: f16 out
__global__ __launch_bounds__(256) void gemm_f16_kernel(
    const f16* __restrict__ A, const f16* __restrict__ BT,
    const float* __restrict__ bias, void* __restrict__ Cout, int M, int N, int K) {
  __shared__ f16 As[128 * GBK];
  __shared__ f16 Bs[128 * GBK];
  int t = threadIdx.x, lane = t & 63, wave = t >> 6;
  int wr = wave >> 1, wc = wave & 1;
  int bx = blockIdx.x, by = blockIdx.y;

  f32x4 acc[4][4];
#pragma unroll
  for (int mi = 0; mi < 4; mi++)
#pragma unroll
    for (int ni = 0; ni < 4; ni++) acc[mi][ni] = (f32x4){0.f, 0.f, 0.f, 0.f};

  const f16* Ablk = A + (size_t)(by * 128) * K;
  const f16* Bblk = BT + (size_t)(bx * 128) * K;
  int rl = lane >> 3;        // row within 8-row group
  int lc = (lane & 7) ^ rl;  // pre-swizzled source chunk (linear LDS dest)

  for (int k0 = 0; k0 < K; k0 += GBK) {
#pragma unroll
    for (int ii = 0; ii < 4; ii++) {
      int i = wave * 4 + ii;
      int r = i * 8 + rl;
      async16(&As[i * 512], Ablk + (size_t)r * K + k0 + lc * 8);
      async16(&Bs[i * 512], Bblk + (size_t)r * K + k0 + lc * 8);
    }
    __syncthreads();
#pragma unroll
    for (int kc = 0; kc < 2; kc++) {
      f16x8 af[4], bf[4];
#pragma unroll
      for (int mi = 0; mi < 4; mi++) {
        int row = wr * 64 + mi * 16 + (lane & 15);
        int pc = (kc * 4 + (lane >> 4)) ^ (row & 7);
        af[mi] = *(const f16x8*)&As[row * 64 + pc * 8];
      }
#pragma unroll
      for (int ni = 0; ni < 4; ni++) {
        int row = wc * 64 + ni * 16 + (lane & 15);
        int pc = (kc * 4 + (lane >> 4)) ^ (row & 7);
        bf[ni] = *(const f16x8*)&Bs[row * 64 + pc * 8];
      }
#pragma unroll
      for (int mi = 0; mi < 4; mi++)
#pragma unroll
        for (int ni = 0; ni < 4; ni++)
          acc[mi][ni] = __builtin_amdgcn_mfma_f32_16x16x32_f16(af[mi], bf[ni], acc[mi][ni], 0, 0, 0);
    }
    __syncthreads();
  }

  int row_base = by * 128 + wr * 64 + (lane >> 4) * 4;
  int col_base = bx * 128 + wc * 64 + (lane & 15);
#pragma unroll
  for (int mi = 0; mi < 4; mi++) {
#pragma unroll
    for (int ni = 0; ni < 4; ni++) {
      int col = col_base + ni * 16;
      float bs = bias[col];
#pragma unroll
      for (int j = 0; j < 4; j++) {
        int row = row_base + mi * 16 + j;
        float x = acc[mi][ni][j] + bs;
        if (GELU) x = 0.5f * x * (1.f + erff(x * 0.70710678118654752f));
        if (OMODE == 0) ((float*)Cout)[(size_t)row * N + col] = x;
        else ((f16*)Cout)[(size_t)row * N + col] = (f16)x;
      }
    }
  }
}

// ---------------- fp16 MFMA GEMM 256x128 (big-M, denser MFMA per barrier) --------
template <int OMODE, bool GELU>
__global__ __launch_bounds__(256) void gemm_f16_bm256_kernel(
    const f16* __restrict__ A, const f16* __restrict__ BT,
    const float* __restrict__ bias, void* __restrict__ Cout, int M, int N, int K) {
  __shared__ f16 As[256 * GBK];  // 32 KB
  __shared__ f16 Bs[128 * GBK];  // 16 KB
  int t = threadIdx.x, lane = t & 63, wave = t >> 6;
  int wr = wave >> 1, wc = wave & 1;  // wr: 128-row half; wc: 64-col half
  int bx = blockIdx.x, by = blockIdx.y;

  f32x4 acc[8][4];
#pragma unroll
  for (int mi = 0; mi < 8; mi++)
#pragma unroll
    for (int ni = 0; ni < 4; ni++) acc[mi][ni] = (f32x4){0.f, 0.f, 0.f, 0.f};

  const f16* Ablk = A + (size_t)(by * 256) * K;
  const f16* Bblk = BT + (size_t)(bx * 128) * K;
  int rl = lane >> 3;
  int lc = (lane & 7) ^ rl;

  for (int k0 = 0; k0 < K; k0 += GBK) {
#pragma unroll
    for (int ii = 0; ii < 8; ii++) {
      int i = wave * 8 + ii;  // 0..31 -> A rows i*8+rl
      int r = i * 8 + rl;
      async16(&As[i * 512], Ablk + (size_t)r * K + k0 + lc * 8);
    }
#pragma unroll
    for (int ii = 0; ii < 4; ii++) {
      int i = wave * 4 + ii;  // 0..15 -> B rows
      int r = i * 8 + rl;
      async16(&Bs[i * 512], Bblk + (size_t)r * K + k0 + lc * 8);
    }
    __syncthreads();
#pragma unroll
    for (int kc = 0; kc < 2; kc++) {
      f16x8 bf[4];
#pragma unroll
      for (int ni = 0; ni < 4; ni++) {
        int row = wc * 64 + ni * 16 + (lane & 15);
        int pc = (kc * 4 + (lane >> 4)) ^ (row & 7);
        bf[ni] = *(const f16x8*)&Bs[row * 64 + pc * 8];
      }
#pragma unroll
      for (int mi = 0; mi < 8; mi++) {
        int row = wr * 128 + mi * 16 + (lane & 15);
        int pc = (kc * 4 + (lane >> 4)) ^ (row & 7);
        f16x8 af = *(const f16x8*)&As[row * 64 + pc * 8];
#pragma unroll
        for (int ni = 0; ni < 4; ni++)
          acc[mi][ni] = __builtin_amdgcn_mfma_f32_16x16x32_f16(af, bf[ni], acc[mi][ni], 0, 0, 0);
      }
    }
    __syncthreads();
  }

  int row_base = by * 256 + wr * 128 + (lane >> 4) * 4;
  int col_base = bx * 128 + wc * 64 + (lane & 15);
#pragma unroll
  for (int mi = 0; mi < 8; mi++) {
#pragma unroll
    for (int ni = 0; ni < 4; ni++) {
      int col = col_base + ni * 16;
      float bs = bias[col];
#pragma unroll
      for (int j = 0; j < 4; j++) {
        int row = row_base + mi * 16 + j;
        float x = acc[mi][ni][j] + bs;
        if (GELU) x = 0.5f * x * (1.f + erff(x * 0.70710678118654752f));
        if (OMODE == 0) ((float*)Cout)[(size_t)row * N + col] = x;
        else ((f16*)Cout)[(size_t)row * N + col] = (f16)x;
      }
    }
  }
}

// ---------------- MFMA local windowed attention ----------------
// block = (head, 64-query block), 256 threads = 4 waves, wave w owns q-cols 16w..16w+15
#define ROWP 72  // padded LDS row: 64 halves + 8 pad (144B) -> bank-spread

__global__ __launch_bounds__(256) void local_attn_mfma_kernel(
    const f16* __restrict__ qkv, const int* __restrict__ amask,
    const int* __restrict__ gmask, const int* __restrict__ gidx,
    const float* __restrict__ gvalid, f16* __restrict__ outp) {
  int h = blockIdx.x >> 6;
  int qb = blockIdx.x & 63;
  int q0 = qb * 64;
  int t = threadIdx.x, lane = t & 63, w = t >> 6;
  int g4 = lane >> 4, l15 = lane & 15;

  __shared__ f16 Qs[64 * ROWP];
  __shared__ f16 Kt[64 * ROWP];      // [k][d]
  __shared__ f16 Vt[64 * ROWP];      // [d][k]  (transposed)
  __shared__ f16 Pb[4 * 16 * ROWP];  // per-wave P^ rows [q][k]
  __shared__ unsigned kokLo, kokHi;
  __shared__ float gvs[NG];

  // ---- stage Q (scaled by 1/8), once ----
  {
    int r = t >> 2, c2 = (t & 3) * 2;
    const f16* qr = qkv + (size_t)(q0 + r) * QKV3 + h * DH + c2 * 8;
    f16x8 v0 = *(const f16x8*)qr;
    f16x8 v1 = *(const f16x8*)(qr + 8);
#pragma unroll
    for (int e = 0; e < 8; e++) { v0[e] = v0[e] * (f16)0.125f; v1[e] = v1[e] * (f16)0.125f; }
    *(f16x8*)&Qs[r * ROWP + c2 * 8] = v0;
    *(f16x8*)&Qs[r * ROWP + c2 * 8 + 8] = v1;
    if (t < NG) gvs[t] = gvalid[t];
  }
  __syncthreads();

  int qrow = w * 16 + l15;
  f16x8 qf0 = *(const f16x8*)&Qs[qrow * ROWP + g4 * 8];
  f16x8 qf1 = *(const f16x8*)&Qs[qrow * ROWP + 32 + g4 * 8];

  float mb = -50000.f, lp = 0.f;
  f32x4 oacc[4];
#pragma unroll
  for (int sd = 0; sd < 4; sd++) oacc[sd] = (f32x4){0.f, 0.f, 0.f, 0.f};

  f16* Pw = &Pb[w * 16 * ROWP];

  for (int kt = 0; kt <= 9; kt++) {
    int jb = q0 - 256 + kt * 64;
    bool isG = (kt == 9);
    if (!isG && (jb + 64 <= 0 || jb >= S)) continue;  // uniform across block
    __syncthreads();
    // ---- stage K tile [k][d] ----
    {
      int k = t >> 2, c2 = (t & 3) * 2;
      int j = isG ? (k < NG ? gidx[k] : -1) : (jb + k);
      bool jv = isG ? (k < NG && gvs[k] > 0.f) : (j >= 0 && j < S);
      f16x8 v0 = {}, v1 = {};
      if (jv) {
        const f16* kr = qkv + (size_t)j * QKV3 + HID + h * DH + c2 * 8;
        v0 = *(const f16x8*)kr; v1 = *(const f16x8*)(kr + 8);
      }
      *(f16x8*)&Kt[k * ROWP + c2 * 8] = v0;
      *(f16x8*)&Kt[k * ROWP + c2 * 8 + 8] = v1;
    }
    // ---- key-ok bitmask (wave 0) ----
    if (w == 0) {
      int k = lane;
      bool ok;
      if (isG) ok = (k < NG && gvs[k] > 0.f);
      else {
        int j = jb + k;
        ok = (j >= 0 && j < S) && (amask[j] != 0) && (gmask[j] == 0);
      }
      unsigned long long m = __ballot(ok);
      if (lane == 0) { kokLo = (unsigned)m; kokHi = (unsigned)(m >> 32); }
    }
    // ---- stage V transposed [d][k], f16x2 writes (pairs of keys) ----
    {
      int k2 = (t & 31) * 2, dq = (t >> 5) * 8;
      int j0 = isG ? (k2 < NG ? gidx[k2] : -1) : (jb + k2);
      int j1 = isG ? (k2 + 1 < NG ? gidx[k2 + 1] : -1) : (jb + k2 + 1);
      bool ok0 = isG ? (k2 < NG && gvs[k2] > 0.f) : (j0 >= 0 && j0 < S);
      bool ok1 = isG ? (k2 + 1 < NG && gvs[k2 + 1] > 0.f) : (j1 >= 0 && j1 < S);
      f16x8 va = {}, vb = {};
      if (ok0) va = *(const f16x8*)(qkv + (size_t)j0 * QKV3 + 2 * HID + h * DH + dq);
      if (ok1) vb = *(const f16x8*)(qkv + (size_t)j1 * QKV3 + 2 * HID + h * DH + dq);
#pragma unroll
      for (int e = 0; e < 8; e++) {
        f16x2 pr = {va[e], vb[e]};
        *(f16x2*)&Vt[(dq + e) * ROWP + k2] = pr;
      }
    }
    __syncthreads();

    unsigned long long kok = ((unsigned long long)kokHi << 32) | (unsigned long long)kokLo;

    // ---- QK^T (swapped): S^T[k][q] ----
    f32x4 sv[4];
    __builtin_amdgcn_s_setprio(1);
#pragma unroll
    for (int s4 = 0; s4 < 4; s4++) {
      int krow = s4 * 16 + l15;
      f16x8 ka0 = *(const f16x8*)&Kt[krow * ROWP + g4 * 8];
      f16x8 ka1 = *(const f16x8*)&Kt[krow * ROWP + 32 + g4 * 8];
      f32x4 a = {0.f, 0.f, 0.f, 0.f};
      a = __builtin_amdgcn_mfma_f32_16x16x32_f16(ka0, qf0, a, 0, 0, 0);
      a = __builtin_amdgcn_mfma_f32_16x16x32_f16(ka1, qf1, a, 0, 0, 0);
      sv[s4] = a;
    }
    __builtin_amdgcn_s_setprio(0);
    // ---- mask (key-ok + band edges on tiles 0/8) ----
    int ql = w * 16 + l15;
#pragma unroll
    for (int s4 = 0; s4 < 4; s4++)
#pragma unroll
      for (int r = 0; r < 4; r++) {
        int kl = s4 * 16 + g4 * 4 + r;
        bool ok = (kok >> kl) & 1ull;
        if (kt == 0) ok = ok && (kl >= ql);
        else if (kt == 8) ok = ok && (kl <= ql);
        sv[s4][r] = ok ? sv[s4][r] : -1e30f;
      }
    // ---- online softmax (per query column) ----
    float mt = -1e30f;
#pragma unroll
    for (int s4 = 0; s4 < 4; s4++)
#pragma unroll
      for (int r = 0; r < 4; r++) mt = fmaxf(mt, sv[s4][r]);
    mt = fmaxf(mt, __shfl_xor(mt, 16));
    mt = fmaxf(mt, __shfl_xor(mt, 32));
    float mn = fmaxf(mb, mt);
    float corr = __expf(mb - mn);
    mb = mn;
    lp *= corr;
#pragma unroll
    for (int sd = 0; sd < 4; sd++)
#pragma unroll
      for (int r = 0; r < 4; r++) oacc[sd][r] *= corr;
    // ---- p = exp(s-m), round to f16, store P^[q][k] ----
#pragma unroll
    for (int s4 = 0; s4 < 4; s4++) {
#pragma unroll
      for (int rp = 0; rp < 2; rp++) {
        float p0 = __expf(sv[s4][rp * 2] - mn);
        float p1 = __expf(sv[s4][rp * 2 + 1] - mn);
        f16 h0 = (f16)p0, h1 = (f16)p1;
        lp += (float)h0 + (float)h1;
        int kl = s4 * 16 + g4 * 4 + rp * 2;
        f16x2 pr = {h0, h1};
        *(f16x2*)&Pw[l15 * ROWP + kl] = pr;
      }
    }
    // ---- PV: O^T[d][q] += V^T @ P^T ----
    f16x8 pf0 = *(const f16x8*)&Pw[l15 * ROWP + g4 * 8];
    f16x8 pf1 = *(const f16x8*)&Pw[l15 * ROWP + 32 + g4 * 8];
    __builtin_amdgcn_s_setprio(1);
#pragma unroll
    for (int sd = 0; sd < 4; sd++) {
      int drow = sd * 16 + l15;
      f16x8 va0 = *(const f16x8*)&Vt[drow * ROWP + g4 * 8];
      f16x8 va1 = *(const f16x8*)&Vt[drow * ROWP + 32 + g4 * 8];
      oacc[sd] = __builtin_amdgcn_mfma_f32_16x16x32_f16(va0, pf0, oacc[sd], 0, 0, 0);
      oacc[sd] = __builtin_amdgcn_mfma_f32_16x16x32_f16(va1, pf1, oacc[sd], 0, 0, 0);
    }
    __builtin_amdgcn_s_setprio(0);
  }

  float lt = lp + __shfl_xor(lp, 16);
  lt = lt + __shfl_xor(lt, 32);
  float inv = (lt > 0.f) ? 1.f / lt : 0.f;
  int qg = q0 + w * 16 + l15;
  f16* orow = outp + (size_t)qg * HID + h * DH;
#pragma unroll
  for (int sd = 0; sd < 4; sd++)
#pragma unroll
    for (int r = 0; r < 4; r++)
      orow[sd * 16 + g4 * 4 + r] = (f16)(oacc[sd][r] * inv);
}

// ============ global-token attention, split-K pipeline ============
__global__ __launch_bounds__(256) void gscore_kernel(
    const f16* __restrict__ qkv, const int* __restrict__ amask,
    const int* __restrict__ gidx, float* __restrict__ Sg) {
  int h = blockIdx.x >> 4, jc = blockIdx.x & 15;
  int t = threadIdx.x;
  __shared__ f16 Qs[NG][DH];
  if (t < 128) {
    int g = t >> 3, c = (t & 7) * 8;
    const f16* qr = qkv + (size_t)gidx[g] * QKV3 + h * DH + c;
    *(f16x8*)&Qs[g][c] = *(const f16x8*)qr;
  }
  __syncthreads();
  int j = jc * 256 + t;
  const f16x8* kr = (const f16x8*)(qkv + (size_t)j * QKV3 + HID + h * DH);
  f16x8 kv[8];
#pragma unroll
  for (int c = 0; c < 8; c++) kv[c] = kr[c];
  bool ok = amask[j] != 0;
#pragma unroll 4
  for (int g = 0; g < NG; g++) {
    float s = 0.f;
#pragma unroll
    for (int c = 0; c < 8; c++) {
      f16x8 qv = *(const f16x8*)&Qs[g][c * 8];
#pragma unroll
      for (int e = 0; e < 8; e++) s += (float)qv[e] * (float)kv[c][e];
    }
    Sg[(size_t)(h * NG + g) * S + j] = ok ? s * 0.125f : NEGV;
  }
}

__global__ __launch_bounds__(256) void gstat_kernel(const float* __restrict__ Sg,
                                                    float* __restrict__ stats) {
  int hg = blockIdx.x;
  const float* row = Sg + (size_t)hg * S;
  __shared__ float red[256];
  int t = threadIdx.x;
  float m = -1e30f;
  for (int j = t; j < S; j += 256) m = fmaxf(m, row[j]);
  m = block_reduce_max(m, red);
  float sum = 0.f;
  for (int j = t; j < S; j += 256) sum += __expf(row[j] - m);
  sum = block_reduce_sum(sum, red);
  if (t == 0) { stats[hg * 2] = m; stats[hg * 2 + 1] = sum; }
}

__global__ __launch_bounds__(256) void gpv_kernel(
    const f16* __restrict__ qkv, const float* __restrict__ Sg,
    const float* __restrict__ stats, float* __restrict__ part) {
  int h = blockIdx.x >> 4, jc = blockIdx.x & 15;
  int jb = jc * 256;
  int t = threadIdx.x;
  __shared__ float Ps[NG][256];
  __shared__ f16 Vs[256][DH];
#pragma unroll
  for (int g = 0; g < NG; g++) {
    int hg = h * NG + g;
    float m = stats[hg * 2], inv = 1.f / stats[hg * 2 + 1];
    Ps[g][t] = __expf(Sg[(size_t)hg * S + jb + t] - m) * inv;
  }
  {
    int r = t >> 3, c = (t & 7) * 8;
#pragma unroll
    for (int pp = 0; pp < 8; pp++) {
      int row = pp * 32 + r;
      const f16* vr = qkv + (size_t)(jb + row) * QKV3 + 2 * HID + h * DH + c;
      *(f16x8*)&Vs[row][c] = *(const f16x8*)vr;
    }
  }
  __syncthreads();
  int d = t & 63, g4 = t >> 6;
  float o0 = 0.f, o1 = 0.f, o2 = 0.f, o3 = 0.f;
#pragma unroll 8
  for (int j = 0; j < 256; j++) {
    float v = (float)Vs[j][d];
    o0 += Ps[g4][j] * v;
    o1 += Ps[g4 + 4][j] * v;
    o2 += Ps[g4 + 8][j] * v;
    o3 += Ps[g4 + 12][j] * v;
  }
  size_t base = ((size_t)h * NG) * 16 * 64;
  part[base + ((size_t)(g4) * 16 + jc) * 64 + d] = o0;
  part[base + ((size_t)(g4 + 4) * 16 + jc) * 64 + d] = o1;
  part[base + ((size_t)(g4 + 8) * 16 + jc) * 64 + d] = o2;
  part[base + ((size_t)(g4 + 12) * 16 + jc) * 64 + d] = o3;
}

__global__ __launch_bounds__(64) void gout_kernel(
    const float* __restrict__ part, const int* __restrict__ gidx,
    const float* __restrict__ gvalid, f16* __restrict__ attn16) {
  int h = blockIdx.x >> 4, g = blockIdx.x & 15;
  if (gvalid[g] <= 0.f) return;
  int d = threadIdx.x;
  const float* pr = part + (((size_t)(h * NG + g)) * 16) * 64 + d;
  float s = 0.f;
#pragma unroll
  for (int jc = 0; jc < 16; jc++) s += pr[jc * 64];
  attn16[(size_t)gidx[g] * HID + h * DH + d] = (f16)s;
}

// ---------------- masked mean pool (partials) + classifier head ----------------
__global__ __launch_bounds__(256) void pool_part_kernel(
    const float* __restrict__ h, const int* __restrict__ amask, float* __restrict__ part) {
  int b = blockIdx.x, t = threadIdx.x;
  float a0 = 0.f, a1 = 0.f, a2 = 0.f;
  for (int r = 0; r < 64; r++) {
    int s = b * 64 + r;
    float w = (float)amask[s];
    const float* hr = h + (size_t)s * HID;
    a0 += hr[t] * w;
    a1 += hr[t + 256] * w;
    a2 += hr[t + 512] * w;
  }
  part[(size_t)b * HID + t] = a0;
  part[(size_t)b * HID + t + 256] = a1;
  part[(size_t)b * HID + t + 512] = a2;
}

__global__ __launch_bounds__(256) void cls_head_kernel(
    const float* __restrict__ part, const int* __restrict__ amask,
    const float* __restrict__ clsW, const float* __restrict__ clsb,
    float* __restrict__ out) {
  __shared__ float pooled[HID];
  __shared__ float red[256];
  int t = threadIdx.x;
  for (int i = t; i < HID; i += 256) {
    float s = 0.f;
    for (int b2 = 0; b2 < 64; b2++) s += part[(size_t)b2 * HID + i];
    pooled[i] = s;
  }
  float c = 0.f;
  for (int s2 = t; s2 < S; s2 += 256) c += (float)amask[s2];
  float cnt = block_reduce_sum(c, red);
  float p0 = 0.f, p1 = 0.f;
  for (int i = t; i < HID; i += 256) {
    float pv = pooled[i] / cnt;
    p0 += pv * clsW[i * 2];
    p1 += pv * clsW[i * 2 + 1];
  }
  float s0 = block_reduce_sum(p0, red);
  float s1 = block_reduce_sum(p1, red);
  if (t == 0) { out[0] = s0 + clsb[0]; out[1] = s1 + clsb[1]; }
}

// ---------------- launch ----------------
extern "C" void kernel_launch(void* const* d_in, const int* in_sizes, int n_in,
                              void* d_out, int out_size, void* d_ws, size_t ws_size,
                              hipStream_t stream) {
  const int* ids = (const int*)d_in[0];
  const int* amask = (const int*)d_in[1];
  const int* gmask = (const int*)d_in[2];
  const float* tok = (const float*)d_in[3];
  const float* pos = (const float*)d_in[4];
  const float* elnw = (const float*)d_in[5];
  const float* elnb = (const float*)d_in[6];
  const float* Wqkv = (const float*)d_in[7];
  const float* bqkv = (const float*)d_in[8];
  const float* Wo = (const float*)d_in[9];
  const float* bo = (const float*)d_in[10];
  const float* ln1w = (const float*)d_in[11];
  const float* ln1b = (const float*)d_in[12];
  const float* W1 = (const float*)d_in[13];
  const float* b1 = (const float*)d_in[14];
  const float* W2 = (const float*)d_in[15];
  const float* b2 = (const float*)d_in[16];
  const float* ln2w = (const float*)d_in[17];
  const float* ln2b = (const float*)d_in[18];
  const float* clsW = (const float*)d_in[19];
  const float* clsb = (const float*)d_in[20];

  char* w8 = (char*)d_ws;
  size_t o = 0;
  float* h = (float*)(w8 + o); o += (size_t)S * HID * 4;
  f16* h16 = (f16*)(w8 + o); o += (size_t)S * HID * 2;
  f16* qkv16 = (f16*)(w8 + o); o += (size_t)S * QKV3 * 2;
  f16* attn16 = (f16*)(w8 + o); o += (size_t)S * HID * 2;
  f16* ff16 = (f16*)(w8 + o); o += (size_t)S * FF * 2;
  float* proj = (float*)(w8 + o); o += (size_t)S * HID * 4;
  float* part = (float*)(w8 + o); o += (size_t)64 * HID * 4;
  int* gidx = (int*)(w8 + o); o += 64;
  float* gvalid = (float*)(w8 + o); o += 64;
  f16* WqkvT = (f16*)(w8 + o); o += (size_t)NLAYER * HID * QKV3 * 2;
  f16* WoT = (f16*)(w8 + o); o += (size_t)NLAYER * HID * HID * 2;
  f16* W1T = (f16*)(w8 + o); o += (size_t)NLAYER * HID * FF * 2;
  f16* W2T = (f16*)(w8 + o); o += (size_t)NLAYER * FF * HID * 2;
  float* Sg = (float*)(w8 + o); o += (size_t)NH * NG * S * 4;
  float* gstats = (float*)(w8 + o); o += (size_t)NH * NG * 2 * 4;
  float* gpart = (float*)(w8 + o); o += (size_t)NH * NG * 16 * 64 * 4;

  gidx_kernel<<<1, 64, 0, stream>>>(gmask, gidx, gvalid);
  embed_ln_kernel<<<S, 256, 0, stream>>>(ids, tok, pos, elnw, elnb, h, h16);
  // all-layer weight conversion upfront (4 launches)
  wt_kernel<<<dim3(QKV3 / 32, HID / 32, NLAYER), 256, 0, stream>>>(Wqkv, WqkvT, HID, QKV3);
  wt_kernel<<<dim3(HID / 32, HID / 32, NLAYER), 256, 0, stream>>>(Wo, WoT, HID, HID);
  wt_kernel<<<dim3(FF / 32, HID / 32, NLAYER), 256, 0, stream>>>(W1, W1T, HID, FF);
  wt_kernel<<<dim3(HID / 32, FF / 32, NLAYER), 256, 0, stream>>>(W2, W2T, FF, HID);

  for (int l = 0; l < NLAYER; l++) {
    gemm_f16_bm256_kernel<1, false><<<dim3(QKV3 / 128, S / 256), 256, 0, stream>>>(
        h16, WqkvT + (size_t)l * HID * QKV3, bqkv + (size_t)l * QKV3, qkv16, S, QKV3, HID);
    local_attn_mfma_kernel<<<NH * 64, 256, 0, stream>>>(
        qkv16, amask, gmask, gidx, gvalid, attn16);
    gscore_kernel<<<NH * 16, 256, 0, stream>>>(qkv16, amask, gidx, Sg);
    gstat_kernel<<<NH * NG, 256, 0, stream>>>(Sg, gstats);
    gpv_kernel<<<NH * 16, 256, 0, stream>>>(qkv16, Sg, gstats, gpart);
    gout_kernel<<<NH * NG, 64, 0, stream>>>(gpart, gidx, gvalid, attn16);
    gemm_f16_kernel<0, false><<<dim3(HID / 128, S / 128), 256, 0, stream>>>(
        attn16, WoT + (size_t)l * HID * HID, bo + (size_t)l * HID, proj, S, HID, HID);
    add_ln_kernel<<<S, 256, 0, stream>>>(h, proj, ln1w + (size_t)l * HID,
                                         ln1b + (size_t)l * HID, h16);
    gemm_f16_bm256_kernel<1, true><<<dim3(FF / 128, S / 256), 256, 0, stream>>>(
        h16, W1T + (size_t)l * HID * FF, b1 + (size_t)l * FF, ff16, S, FF, HID);
    gemm_f16_kernel<0, false><<<dim3(HID / 128, S / 128), 256, 0, stream>>>(
        ff16, W2T + (size_t)l * FF * HID, b2 + (size_t)l * HID, proj, S, HID, FF);
    add_ln_kernel<<<S, 256, 0, stream>>>(h, proj, ln2w + (size_t)l * HID,
                                         ln2b + (size_t)l * HID, h16);
  }
  pool_part_kernel<<<64, 256, 0, stream>>>(h, amask, part);
  cls_head_kernel<<<1, 256, 0, stream>>>(part, amask, clsW, clsb, (float*)d_out);
}

// Round 6
// 3134.640 us; speedup vs baseline: 1.4124x; 1.4124x over previous
//
#include <hip/hip_runtime.h>
#include <cmath>

#define S 4096
#define HID 768
#define NH 12
#define DH 64
#define CHUNK 256
#define NC (S / CHUNK)
#define NG 16
#define FF 3072
#define NLAYER 12
#define QKV3 (3 * HID)
#define NEGV -1e9f

typedef _Float16 f16;
typedef __attribute__((ext_vector_type(2))) _Float16 f16x2;
typedef __attribute__((ext_vector_type(4))) _Float16 f16x4;
typedef __attribute__((ext_vector_type(8))) _Float16 f16x8;
typedef __attribute__((ext_vector_type(4))) float f32x4;

__device__ __forceinline__ void async16(f16* lds, const f16* g) {
  __builtin_amdgcn_global_load_lds((const __attribute__((address_space(1))) unsigned int*)g,
                                   (__attribute__((address_space(3))) unsigned int*)lds,
                                   16, 0, 0);
}

// ---------------- block reduction helpers (blockDim.x == 256) ----------------
__device__ __forceinline__ float block_reduce_sum(float v, float* red) {
  int t = threadIdx.x;
  red[t] = v; __syncthreads();
  for (int st = 128; st > 0; st >>= 1) {
    if (t < st) red[t] += red[t + st];
    __syncthreads();
  }
  float r = red[0]; __syncthreads();
  return r;
}
__device__ __forceinline__ float block_reduce_max(float v, float* red) {
  int t = threadIdx.x;
  red[t] = v; __syncthreads();
  for (int st = 128; st > 0; st >>= 1) {
    if (t < st) red[t] = fmaxf(red[t], red[t + st]);
    __syncthreads();
  }
  float r = red[0]; __syncthreads();
  return r;
}

// ---------------- gidx / gvalid (matches jax top_k semantics) ----------------
__global__ void gidx_kernel(const int* __restrict__ gmask, int* __restrict__ gidx,
                            float* __restrict__ gvalid) {
  if (threadIdx.x != 0 || blockIdx.x != 0) return;
  int cnt = 0;
  for (int s = 0; s < S && cnt < NG; s++)
    if (gmask[s] > 0) { gidx[cnt] = s; gvalid[cnt] = 1.f; cnt++; }
  for (int s = 0; s < S && cnt < NG; s++)
    if (gmask[s] == 0) { gidx[cnt] = s; gvalid[cnt] = 0.f; cnt++; }
}

// ---------------- embedding + LayerNorm (writes f32 + f16) ----------------
__global__ __launch_bounds__(256) void embed_ln_kernel(
    const int* __restrict__ ids, const float* __restrict__ tok,
    const float* __restrict__ pos, const float* __restrict__ g,
    const float* __restrict__ b, float* __restrict__ h, f16* __restrict__ h16) {
  int s = blockIdx.x, t = threadIdx.x;
  __shared__ float xs[HID];
  __shared__ float red[256];
  const float* tr = tok + (size_t)ids[s] * HID;
  const float* pr = pos + (size_t)s * HID;
  float ls = 0.f;
  for (int i = t; i < HID; i += 256) { float v = tr[i] + pr[i]; xs[i] = v; ls += v; }
  float mu = block_reduce_sum(ls, red) * (1.f / HID);
  float lv = 0.f;
  for (int i = t; i < HID; i += 256) { float d = xs[i] - mu; lv += d * d; }
  float var = block_reduce_sum(lv, red) * (1.f / HID);
  float inv = rsqrtf(var + 1e-5f);
  for (int i = t; i < HID; i += 256) {
    float o = (xs[i] - mu) * inv * g[i] + b[i];
    h[(size_t)s * HID + i] = o;
    h16[(size_t)s * HID + i] = (f16)o;
  }
}

// ---------------- residual add + LayerNorm (in-place on h, also f16) ----------------
__global__ __launch_bounds__(256) void add_ln_kernel(
    float* __restrict__ h, const float* __restrict__ x2,
    const float* __restrict__ g, const float* __restrict__ b, f16* __restrict__ h16) {
  int s = blockIdx.x, t = threadIdx.x;
  __shared__ float xs[HID];
  __shared__ float red[256];
  float ls = 0.f;
  for (int i = t; i < HID; i += 256) {
    float v = h[(size_t)s * HID + i] + x2[(size_t)s * HID + i];
    xs[i] = v; ls += v;
  }
  float mu = block_reduce_sum(ls, red) * (1.f / HID);
  float lv = 0.f;
  for (int i = t; i < HID; i += 256) { float d = xs[i] - mu; lv += d * d; }
  float var = block_reduce_sum(lv, red) * (1.f / HID);
  float inv = rsqrtf(var + 1e-5f);
  for (int i = t; i < HID; i += 256) {
    float o = (xs[i] - mu) * inv * g[i] + b[i];
    h[(size_t)s * HID + i] = o;
    h16[(size_t)s * HID + i] = (f16)o;
  }
}

// ------ weight transpose + f16 convert, ALL layers: W[l][K][N] f32 -> WT[l][N][K] f16
__global__ __launch_bounds__(256) void wt_kernel(const float* __restrict__ W,
                                                 f16* __restrict__ WT, int K, int N) {
  size_t lo = (size_t)blockIdx.z * K * N;
  const float* Wl = W + lo;
  f16* WTl = WT + lo;
  __shared__ float tile[32][33];
  int k0 = blockIdx.y * 32, n0 = blockIdx.x * 32;
  int t = threadIdx.x;
  int r = t >> 3, c = (t & 7) * 4;
  float4 v = *(const float4*)&Wl[(size_t)(k0 + r) * N + n0 + c];
  tile[r][c] = v.x; tile[r][c + 1] = v.y; tile[r][c + 2] = v.z; tile[r][c + 3] = v.w;
  __syncthreads();
  int n = t >> 3, kq = (t & 7) * 4;
  f16x4 o = {(f16)tile[kq][n], (f16)tile[kq + 1][n], (f16)tile[kq + 2][n], (f16)tile[kq + 3][n]};
  *(f16x4*)&WTl[(size_t)(n0 + n) * K + k0 + kq] = o;
}

// ------- fp16 MFMA GEMM 128x128, double-buffered 1-barrier pipeline -------
// C = A(f16,[M][K]) @ BT(f16,[N][K])^T + bias
#define GBK 64

template <int OMODE, bool GELU>  // OMODE 0: f32 out, 1: f16 out
__global__ __launch_bounds__(256) void gemm_f16_kernel(
    const f16* __restrict__ A, const f16* __restrict__ BT,
    const float* __restrict__ bias, void* __restrict__ Cout, int M, int N, int K) {
  __shared__ f16 As[2][128 * GBK];  // 16 KB each
  __shared__ f16 Bs[2][128 * GBK];
  int t = threadIdx.x, lane = t & 63, wave = t >> 6;
  int wr = wave >> 1, wc = wave & 1;
  int bx = blockIdx.x, by = blockIdx.y;

  f32x4 acc[4][4];
#pragma unroll
  for (int mi = 0; mi < 4; mi++)
#pragma unroll
    for (int ni = 0; ni < 4; ni++) acc[mi][ni] = (f32x4){0.f, 0.f, 0.f, 0.f};

  const f16* Ablk = A + (size_t)(by * 128) * K;
  const f16* Bblk = BT + (size_t)(bx * 128) * K;
  int rl = lane >> 3;        // row within 8-row group
  int lc = (lane & 7) ^ rl;  // pre-swizzled source chunk (linear LDS dest)

  // stage one K-tile into buffer `buf` (4 A-chunks + 4 B-chunks per wave)
#define STAGE(buf, k0)                                                     \
  {                                                                        \
    _Pragma("unroll") for (int ii = 0; ii < 4; ii++) {                     \
      int i = wave * 4 + ii;                                               \
      int r = i * 8 + rl;                                                  \
      async16(&As[buf][i * 512], Ablk + (size_t)r * K + (k0) + lc * 8);    \
      async16(&Bs[buf][i * 512], Bblk + (size_t)r * K + (k0) + lc * 8);    \
    }                                                                      \
  }

  int nt = K / GBK;
  STAGE(0, 0);
  __syncthreads();  // drain prologue loads (compiler emits vmcnt(0) before barrier)
  int cur = 0;
  for (int tt = 0; tt < nt; tt++) {
    if (tt + 1 < nt) STAGE(cur ^ 1, (tt + 1) * GBK);  // prefetch next tile
#pragma unroll
    for (int kc = 0; kc < 2; kc++) {
      f16x8 af[4], bf[4];
#pragma unroll
      for (int mi = 0; mi < 4; mi++) {
        int row = wr * 64 + mi * 16 + (lane & 15);
        int pc = (kc * 4 + (lane >> 4)) ^ (row & 7);
        af[mi] = *(const f16x8*)&As[cur][row * 64 + pc * 8];
      }
#pragma unroll
      for (int ni = 0; ni < 4; ni++) {
        int row = wc * 64 + ni * 16 + (lane & 15);
        int pc = (kc * 4 + (lane >> 4)) ^ (row & 7);
        bf[ni] = *(const f16x8*)&Bs[cur][row * 64 + pc * 8];
      }
#pragma unroll
      for (int mi = 0; mi < 4; mi++)
#pragma unroll
        for (int ni = 0; ni < 4; ni++)
          acc[mi][ni] = __builtin_amdgcn_mfma_f32_16x16x32_f16(af[mi], bf[ni], acc[mi][ni], 0, 0, 0);
    }
    __syncthreads();  // drains prefetch loads; everyone done reading buf[cur]
    cur ^= 1;
  }
#undef STAGE

  int row_base = by * 128 + wr * 64 + (lane >> 4) * 4;
  int col_base = bx * 128 + wc * 64 + (lane & 15);
#pragma unroll
  for (int mi = 0; mi < 4; mi++) {
#pragma unroll
    for (int ni = 0; ni < 4; ni++) {
      int col = col_base + ni * 16;
      float bs = bias[col];
#pragma unroll
      for (int j = 0; j < 4; j++) {
        int row = row_base + mi * 16 + j;
        float x = acc[mi][ni][j] + bs;
        if (GELU) x = 0.5f * x * (1.f + erff(x * 0.70710678118654752f));
        if (OMODE == 0) ((float*)Cout)[(size_t)row * N + col] = x;
        else ((f16*)Cout)[(size_t)row * N + col] = (f16)x;
      }
    }
  }
}

// ---------------- MFMA local windowed attention ----------------
// block = (head, 64-query block), 256 threads = 4 waves, wave w owns q-cols 16w..16w+15
#define ROWP 72  // padded LDS row: 64 halves + 8 pad (144B) -> bank-spread

__global__ __launch_bounds__(256) void local_attn_mfma_kernel(
    const f16* __restrict__ qkv, const int* __restrict__ amask,
    const int* __restrict__ gmask, const int* __restrict__ gidx,
    const float* __restrict__ gvalid, f16* __restrict__ outp) {
  int h = blockIdx.x >> 6;
  int qb = blockIdx.x & 63;
  int q0 = qb * 64;
  int t = threadIdx.x, lane = t & 63, w = t >> 6;
  int g4 = lane >> 4, l15 = lane & 15;

  __shared__ f16 Qs[64 * ROWP];
  __shared__ f16 Kt[64 * ROWP];      // [k][d]
  __shared__ f16 Vt[64 * ROWP];      // [d][k]  (transposed)
  __shared__ f16 Pb[4 * 16 * ROWP];  // per-wave P^ rows [q][k]
  __shared__ unsigned kokLo, kokHi;
  __shared__ float gvs[NG];

  // ---- stage Q (scaled by 1/8), once ----
  {
    int r = t >> 2, c2 = (t & 3) * 2;
    const f16* qr = qkv + (size_t)(q0 + r) * QKV3 + h * DH + c2 * 8;
    f16x8 v0 = *(const f16x8*)qr;
    f16x8 v1 = *(const f16x8*)(qr + 8);
#pragma unroll
    for (int e = 0; e < 8; e++) { v0[e] = v0[e] * (f16)0.125f; v1[e] = v1[e] * (f16)0.125f; }
    *(f16x8*)&Qs[r * ROWP + c2 * 8] = v0;
    *(f16x8*)&Qs[r * ROWP + c2 * 8 + 8] = v1;
    if (t < NG) gvs[t] = gvalid[t];
  }
  __syncthreads();

  int qrow = w * 16 + l15;
  f16x8 qf0 = *(const f16x8*)&Qs[qrow * ROWP + g4 * 8];
  f16x8 qf1 = *(const f16x8*)&Qs[qrow * ROWP + 32 + g4 * 8];

  float mb = -50000.f, lp = 0.f;
  f32x4 oacc[4];
#pragma unroll
  for (int sd = 0; sd < 4; sd++) oacc[sd] = (f32x4){0.f, 0.f, 0.f, 0.f};

  f16* Pw = &Pb[w * 16 * ROWP];

  for (int kt = 0; kt <= 9; kt++) {
    int jb = q0 - 256 + kt * 64;
    bool isG = (kt == 9);
    if (!isG && (jb + 64 <= 0 || jb >= S)) continue;  // uniform across block
    __syncthreads();
    // ---- stage K tile [k][d] ----
    {
      int k = t >> 2, c2 = (t & 3) * 2;
      int j = isG ? (k < NG ? gidx[k] : -1) : (jb + k);
      bool jv = isG ? (k < NG && gvs[k] > 0.f) : (j >= 0 && j < S);
      f16x8 v0 = {}, v1 = {};
      if (jv) {
        const f16* kr = qkv + (size_t)j * QKV3 + HID + h * DH + c2 * 8;
        v0 = *(const f16x8*)kr; v1 = *(const f16x8*)(kr + 8);
      }
      *(f16x8*)&Kt[k * ROWP + c2 * 8] = v0;
      *(f16x8*)&Kt[k * ROWP + c2 * 8 + 8] = v1;
    }
    // ---- key-ok bitmask (wave 0) ----
    if (w == 0) {
      int k = lane;
      bool ok;
      if (isG) ok = (k < NG && gvs[k] > 0.f);
      else {
        int j = jb + k;
        ok = (j >= 0 && j < S) && (amask[j] != 0) && (gmask[j] == 0);
      }
      unsigned long long m = __ballot(ok);
      if (lane == 0) { kokLo = (unsigned)m; kokHi = (unsigned)(m >> 32); }
    }
    // ---- stage V transposed [d][k], f16x2 writes (pairs of keys) ----
    {
      int k2 = (t & 31) * 2, dq = (t >> 5) * 8;
      int j0 = isG ? (k2 < NG ? gidx[k2] : -1) : (jb + k2);
      int j1 = isG ? (k2 + 1 < NG ? gidx[k2 + 1] : -1) : (jb + k2 + 1);
      bool ok0 = isG ? (k2 < NG && gvs[k2] > 0.f) : (j0 >= 0 && j0 < S);
      bool ok1 = isG ? (k2 + 1 < NG && gvs[k2 + 1] > 0.f) : (j1 >= 0 && j1 < S);
      f16x8 va = {}, vb = {};
      if (ok0) va = *(const f16x8*)(qkv + (size_t)j0 * QKV3 + 2 * HID + h * DH + dq);
      if (ok1) vb = *(const f16x8*)(qkv + (size_t)j1 * QKV3 + 2 * HID + h * DH + dq);
#pragma unroll
      for (int e = 0; e < 8; e++) {
        f16x2 pr = {va[e], vb[e]};
        *(f16x2*)&Vt[(dq + e) * ROWP + k2] = pr;
      }
    }
    __syncthreads();

    unsigned long long kok = ((unsigned long long)kokHi << 32) | (unsigned long long)kokLo;

    // ---- QK^T (swapped): S^T[k][q] ----
    f32x4 sv[4];
    __builtin_amdgcn_s_setprio(1);
#pragma unroll
    for (int s4 = 0; s4 < 4; s4++) {
      int krow = s4 * 16 + l15;
      f16x8 ka0 = *(const f16x8*)&Kt[krow * ROWP + g4 * 8];
      f16x8 ka1 = *(const f16x8*)&Kt[krow * ROWP + 32 + g4 * 8];
      f32x4 a = {0.f, 0.f, 0.f, 0.f};
      a = __builtin_amdgcn_mfma_f32_16x16x32_f16(ka0, qf0, a, 0, 0, 0);
      a = __builtin_amdgcn_mfma_f32_16x16x32_f16(ka1, qf1, a, 0, 0, 0);
      sv[s4] = a;
    }
    __builtin_amdgcn_s_setprio(0);
    // ---- mask (key-ok + band edges on tiles 0/8) ----
    int ql = w * 16 + l15;
#pragma unroll
    for (int s4 = 0; s4 < 4; s4++)
#pragma unroll
      for (int r = 0; r < 4; r++) {
        int kl = s4 * 16 + g4 * 4 + r;
        bool ok = (kok >> kl) & 1ull;
        if (kt == 0) ok = ok && (kl >= ql);
        else if (kt == 8) ok = ok && (kl <= ql);
        sv[s4][r] = ok ? sv[s4][r] : -1e30f;
      }
    // ---- online softmax (per query column) ----
    float mt = -1e30f;
#pragma unroll
    for (int s4 = 0; s4 < 4; s4++)
#pragma unroll
      for (int r = 0; r < 4; r++) mt = fmaxf(mt, sv[s4][r]);
    mt = fmaxf(mt, __shfl_xor(mt, 16));
    mt = fmaxf(mt, __shfl_xor(mt, 32));
    float mn = fmaxf(mb, mt);
    float corr = __expf(mb - mn);
    mb = mn;
    lp *= corr;
#pragma unroll
    for (int sd = 0; sd < 4; sd++)
#pragma unroll
      for (int r = 0; r < 4; r++) oacc[sd][r] *= corr;
    // ---- p = exp(s-m), round to f16, store P^[q][k] ----
#pragma unroll
    for (int s4 = 0; s4 < 4; s4++) {
#pragma unroll
      for (int rp = 0; rp < 2; rp++) {
        float p0 = __expf(sv[s4][rp * 2] - mn);
        float p1 = __expf(sv[s4][rp * 2 + 1] - mn);
        f16 h0 = (f16)p0, h1 = (f16)p1;
        lp += (float)h0 + (float)h1;
        int kl = s4 * 16 + g4 * 4 + rp * 2;
        f16x2 pr = {h0, h1};
        *(f16x2*)&Pw[l15 * ROWP + kl] = pr;
      }
    }
    // ---- PV: O^T[d][q] += V^T @ P^T ----
    f16x8 pf0 = *(const f16x8*)&Pw[l15 * ROWP + g4 * 8];
    f16x8 pf1 = *(const f16x8*)&Pw[l15 * ROWP + 32 + g4 * 8];
    __builtin_amdgcn_s_setprio(1);
#pragma unroll
    for (int sd = 0; sd < 4; sd++) {
      int drow = sd * 16 + l15;
      f16x8 va0 = *(const f16x8*)&Vt[drow * ROWP + g4 * 8];
      f16x8 va1 = *(const f16x8*)&Vt[drow * ROWP + 32 + g4 * 8];
      oacc[sd] = __builtin_amdgcn_mfma_f32_16x16x32_f16(va0, pf0, oacc[sd], 0, 0, 0);
      oacc[sd] = __builtin_amdgcn_mfma_f32_16x16x32_f16(va1, pf1, oacc[sd], 0, 0, 0);
    }
    __builtin_amdgcn_s_setprio(0);
  }

  float lt = lp + __shfl_xor(lp, 16);
  lt = lt + __shfl_xor(lt, 32);
  float inv = (lt > 0.f) ? 1.f / lt : 0.f;
  int qg = q0 + w * 16 + l15;
  f16* orow = outp + (size_t)qg * HID + h * DH;
#pragma unroll
  for (int sd = 0; sd < 4; sd++)
#pragma unroll
    for (int r = 0; r < 4; r++)
      orow[sd * 16 + g4 * 4 + r] = (f16)(oacc[sd][r] * inv);
}

// ============ global-token attention, split-K pipeline ============
__global__ __launch_bounds__(256) void gscore_kernel(
    const f16* __restrict__ qkv, const int* __restrict__ amask,
    const int* __restrict__ gidx, float* __restrict__ Sg) {
  int h = blockIdx.x >> 4, jc = blockIdx.x & 15;
  int t = threadIdx.x;
  __shared__ f16 Qs[NG][DH];
  if (t < 128) {
    int g = t >> 3, c = (t & 7) * 8;
    const f16* qr = qkv + (size_t)gidx[g] * QKV3 + h * DH + c;
    *(f16x8*)&Qs[g][c] = *(const f16x8*)qr;
  }
  __syncthreads();
  int j = jc * 256 + t;
  const f16x8* kr = (const f16x8*)(qkv + (size_t)j * QKV3 + HID + h * DH);
  f16x8 kv[8];
#pragma unroll
  for (int c = 0; c < 8; c++) kv[c] = kr[c];
  bool ok = amask[j] != 0;
#pragma unroll 4
  for (int g = 0; g < NG; g++) {
    float s = 0.f;
#pragma unroll
    for (int c = 0; c < 8; c++) {
      f16x8 qv = *(const f16x8*)&Qs[g][c * 8];
#pragma unroll
      for (int e = 0; e < 8; e++) s += (float)qv[e] * (float)kv[c][e];
    }
    Sg[(size_t)(h * NG + g) * S + j] = ok ? s * 0.125f : NEGV;
  }
}

__global__ __launch_bounds__(256) void gstat_kernel(const float* __restrict__ Sg,
                                                    float* __restrict__ stats) {
  int hg = blockIdx.x;
  const float* row = Sg + (size_t)hg * S;
  __shared__ float red[256];
  int t = threadIdx.x;
  float m = -1e30f;
  for (int j = t; j < S; j += 256) m = fmaxf(m, row[j]);
  m = block_reduce_max(m, red);
  float sum = 0.f;
  for (int j = t; j < S; j += 256) sum += __expf(row[j] - m);
  sum = block_reduce_sum(sum, red);
  if (t == 0) { stats[hg * 2] = m; stats[hg * 2 + 1] = sum; }
}

__global__ __launch_bounds__(256) void gpv_kernel(
    const f16* __restrict__ qkv, const float* __restrict__ Sg,
    const float* __restrict__ stats, float* __restrict__ part) {
  int h = blockIdx.x >> 4, jc = blockIdx.x & 15;
  int jb = jc * 256;
  int t = threadIdx.x;
  __shared__ float Ps[NG][256];
  __shared__ f16 Vs[256][DH];
#pragma unroll
  for (int g = 0; g < NG; g++) {
    int hg = h * NG + g;
    float m = stats[hg * 2], inv = 1.f / stats[hg * 2 + 1];
    Ps[g][t] = __expf(Sg[(size_t)hg * S + jb + t] - m) * inv;
  }
  {
    int r = t >> 3, c = (t & 7) * 8;
#pragma unroll
    for (int pp = 0; pp < 8; pp++) {
      int row = pp * 32 + r;
      const f16* vr = qkv + (size_t)(jb + row) * QKV3 + 2 * HID + h * DH + c;
      *(f16x8*)&Vs[row][c] = *(const f16x8*)vr;
    }
  }
  __syncthreads();
  int d = t & 63, g4 = t >> 6;
  float o0 = 0.f, o1 = 0.f, o2 = 0.f, o3 = 0.f;
#pragma unroll 8
  for (int j = 0; j < 256; j++) {
    float v = (float)Vs[j][d];
    o0 += Ps[g4][j] * v;
    o1 += Ps[g4 + 4][j] * v;
    o2 += Ps[g4 + 8][j] * v;
    o3 += Ps[g4 + 12][j] * v;
  }
  size_t base = ((size_t)h * NG) * 16 * 64;
  part[base + ((size_t)(g4) * 16 + jc) * 64 + d] = o0;
  part[base + ((size_t)(g4 + 4) * 16 + jc) * 64 + d] = o1;
  part[base + ((size_t)(g4 + 8) * 16 + jc) * 64 + d] = o2;
  part[base + ((size_t)(g4 + 12) * 16 + jc) * 64 + d] = o3;
}

__global__ __launch_bounds__(64) void gout_kernel(
    const float* __restrict__ part, const int* __restrict__ gidx,
    const float* __restrict__ gvalid, f16* __restrict__ attn16) {
  int h = blockIdx.x >> 4, g = blockIdx.x & 15;
  if (gvalid[g] <= 0.f) return;
  int d = threadIdx.x;
  const float* pr = part + (((size_t)(h * NG + g)) * 16) * 64 + d;
  float s = 0.f;
#pragma unroll
  for (int jc = 0; jc < 16; jc++) s += pr[jc * 64];
  attn16[(size_t)gidx[g] * HID + h * DH + d] = (f16)s;
}

// ---------------- masked mean pool (partials) + classifier head ----------------
__global__ __launch_bounds__(256) void pool_part_kernel(
    const float* __restrict__ h, const int* __restrict__ amask, float* __restrict__ part) {
  int b = blockIdx.x, t = threadIdx.x;
  float a0 = 0.f, a1 = 0.f, a2 = 0.f;
  for (int r = 0; r < 64; r++) {
    int s = b * 64 + r;
    float w = (float)amask[s];
    const float* hr = h + (size_t)s * HID;
    a0 += hr[t] * w;
    a1 += hr[t + 256] * w;
    a2 += hr[t + 512] * w;
  }
  part[(size_t)b * HID + t] = a0;
  part[(size_t)b * HID + t + 256] = a1;
  part[(size_t)b * HID + t + 512] = a2;
}

__global__ __launch_bounds__(256) void cls_head_kernel(
    const float* __restrict__ part, const int* __restrict__ amask,
    const float* __restrict__ clsW, const float* __restrict__ clsb,
    float* __restrict__ out) {
  __shared__ float pooled[HID];
  __shared__ float red[256];
  int t = threadIdx.x;
  for (int i = t; i < HID; i += 256) {
    float s = 0.f;
    for (int b2 = 0; b2 < 64; b2++) s += part[(size_t)b2 * HID + i];
    pooled[i] = s;
  }
  float c = 0.f;
  for (int s2 = t; s2 < S; s2 += 256) c += (float)amask[s2];
  float cnt = block_reduce_sum(c, red);
  float p0 = 0.f, p1 = 0.f;
  for (int i = t; i < HID; i += 256) {
    float pv = pooled[i] / cnt;
    p0 += pv * clsW[i * 2];
    p1 += pv * clsW[i * 2 + 1];
  }
  float s0 = block_reduce_sum(p0, red);
  float s1 = block_reduce_sum(p1, red);
  if (t == 0) { out[0] = s0 + clsb[0]; out[1] = s1 + clsb[1]; }
}

// ---------------- launch ----------------
extern "C" void kernel_launch(void* const* d_in, const int* in_sizes, int n_in,
                              void* d_out, int out_size, void* d_ws, size_t ws_size,
                              hipStream_t stream) {
  const int* ids = (const int*)d_in[0];
  const int* amask = (const int*)d_in[1];
  const int* gmask = (const int*)d_in[2];
  const float* tok = (const float*)d_in[3];
  const float* pos = (const float*)d_in[4];
  const float* elnw = (const float*)d_in[5];
  const float* elnb = (const float*)d_in[6];
  const float* Wqkv = (const float*)d_in[7];
  const float* bqkv = (const float*)d_in[8];
  const float* Wo = (const float*)d_in[9];
  const float* bo = (const float*)d_in[10];
  const float* ln1w = (const float*)d_in[11];
  const float* ln1b = (const float*)d_in[12];
  const float* W1 = (const float*)d_in[13];
  const float* b1 = (const float*)d_in[14];
  const float* W2 = (const float*)d_in[15];
  const float* b2 = (const float*)d_in[16];
  const float* ln2w = (const float*)d_in[17];
  const float* ln2b = (const float*)d_in[18];
  const float* clsW = (const float*)d_in[19];
  const float* clsb = (const float*)d_in[20];

  char* w8 = (char*)d_ws;
  size_t o = 0;
  float* h = (float*)(w8 + o); o += (size_t)S * HID * 4;
  f16* h16 = (f16*)(w8 + o); o += (size_t)S * HID * 2;
  f16* qkv16 = (f16*)(w8 + o); o += (size_t)S * QKV3 * 2;
  f16* attn16 = (f16*)(w8 + o); o += (size_t)S * HID * 2;
  f16* ff16 = (f16*)(w8 + o); o += (size_t)S * FF * 2;
  float* proj = (float*)(w8 + o); o += (size_t)S * HID * 4;
  float* part = (float*)(w8 + o); o += (size_t)64 * HID * 4;
  int* gidx = (int*)(w8 + o); o += 64;
  float* gvalid = (float*)(w8 + o); o += 64;
  f16* WqkvT = (f16*)(w8 + o); o += (size_t)NLAYER * HID * QKV3 * 2;
  f16* WoT = (f16*)(w8 + o); o += (size_t)NLAYER * HID * HID * 2;
  f16* W1T = (f16*)(w8 + o); o += (size_t)NLAYER * HID * FF * 2;
  f16* W2T = (f16*)(w8 + o); o += (size_t)NLAYER * FF * HID * 2;
  float* Sg = (float*)(w8 + o); o += (size_t)NH * NG * S * 4;
  float* gstats = (float*)(w8 + o); o += (size_t)NH * NG * 2 * 4;
  float* gpart = (float*)(w8 + o); o += (size_t)NH * NG * 16 * 64 * 4;

  gidx_kernel<<<1, 64, 0, stream>>>(gmask, gidx, gvalid);
  embed_ln_kernel<<<S, 256, 0, stream>>>(ids, tok, pos, elnw, elnb, h, h16);
  // all-layer weight conversion upfront (4 launches)
  wt_kernel<<<dim3(QKV3 / 32, HID / 32, NLAYER), 256, 0, stream>>>(Wqkv, WqkvT, HID, QKV3);
  wt_kernel<<<dim3(HID / 32, HID / 32, NLAYER), 256, 0, stream>>>(Wo, WoT, HID, HID);
  wt_kernel<<<dim3(FF / 32, HID / 32, NLAYER), 256, 0, stream>>>(W1, W1T, HID, FF);
  wt_kernel<<<dim3(HID / 32, FF / 32, NLAYER), 256, 0, stream>>>(W2, W2T, FF, HID);

  for (int l = 0; l < NLAYER; l++) {
    gemm_f16_kernel<1, false><<<dim3(QKV3 / 128, S / 128), 256, 0, stream>>>(
        h16, WqkvT + (size_t)l * HID * QKV3, bqkv + (size_t)l * QKV3, qkv16, S, QKV3, HID);
    local_attn_mfma_kernel<<<NH * 64, 256, 0, stream>>>(
        qkv16, amask, gmask, gidx, gvalid, attn16);
    gscore_kernel<<<NH * 16, 256, 0, stream>>>(qkv16, amask, gidx, Sg);
    gstat_kernel<<<NH * NG, 256, 0, stream>>>(Sg, gstats);
    gpv_kernel<<<NH * 16, 256, 0, stream>>>(qkv16, Sg, gstats, gpart);
    gout_kernel<<<NH * NG, 64, 0, stream>>>(gpart, gidx, gvalid, attn16);
    gemm_f16_kernel<0, false><<<dim3(HID / 128, S / 128), 256, 0, stream>>>(
        attn16, WoT + (size_t)l * HID * HID, bo + (size_t)l * HID, proj, S, HID, HID);
    add_ln_kernel<<<S, 256, 0, stream>>>(h, proj, ln1w + (size_t)l * HID,
                                         ln1b + (size_t)l * HID, h16);
    gemm_f16_kernel<1, true><<<dim3(FF / 128, S / 128), 256, 0, stream>>>(
        h16, W1T + (size_t)l * HID * FF, b1 + (size_t)l * FF, ff16, S, FF, HID);
    gemm_f16_kernel<0, false><<<dim3(HID / 128, S / 128), 256, 0, stream>>>(
        ff16, W2T + (size_t)l * FF * HID, b2 + (size_t)l * HID, proj, S, HID, FF);
    add_ln_kernel<<<S, 256, 0, stream>>>(h, proj, ln2w + (size_t)l * HID,
                                         ln2b + (size_t)l * HID, h16);
  }
  pool_part_kernel<<<64, 256, 0, stream>>>(h, amask, part);
  cls_head_kernel<<<1, 256, 0, stream>>>(part, amask, clsW, clsb, (float*)d_out);
}

// Round 7
// 2586.474 us; speedup vs baseline: 1.7118x; 1.2119x over previous
//
#include <hip/hip_runtime.h>
#include <cmath>

#define S 4096
#define HID 768
#define NH 12
#define DH 64
#define CHUNK 256
#define NC (S / CHUNK)
#define NG 16
#define FF 3072
#define NLAYER 12
#define QKV3 (3 * HID)
#define NEGV -1e9f

typedef _Float16 f16;
typedef __attribute__((ext_vector_type(2))) _Float16 f16x2;
typedef __attribute__((ext_vector_type(4))) _Float16 f16x4;
typedef __attribute__((ext_vector_type(8))) _Float16 f16x8;
typedef __attribute__((ext_vector_type(4))) float f32x4;

__device__ __forceinline__ void async16(f16* lds, const f16* g) {
  __builtin_amdgcn_global_load_lds((const __attribute__((address_space(1))) unsigned int*)g,
                                   (__attribute__((address_space(3))) unsigned int*)lds,
                                   16, 0, 0);
}

// bijective XCD swizzle for nwg % 8 == 0: dispatch-block i computes tile
// (i%8)*(nwg/8) + i/8, so each XCD's round-robin share is a contiguous tile range.
__device__ __forceinline__ int xcd_swz(int lin, int nwg) {
  return (lin & 7) * (nwg >> 3) + (lin >> 3);
}

// ---------------- block reduction helpers (blockDim.x == 256) ----------------
__device__ __forceinline__ float block_reduce_sum(float v, float* red) {
  int t = threadIdx.x;
  red[t] = v; __syncthreads();
  for (int st = 128; st > 0; st >>= 1) {
    if (t < st) red[t] += red[t + st];
    __syncthreads();
  }
  float r = red[0]; __syncthreads();
  return r;
}

// ---------------- gidx / gvalid (matches jax top_k semantics) ----------------
__global__ void gidx_kernel(const int* __restrict__ gmask, int* __restrict__ gidx,
                            float* __restrict__ gvalid) {
  if (threadIdx.x != 0 || blockIdx.x != 0) return;
  int cnt = 0;
  for (int s = 0; s < S && cnt < NG; s++)
    if (gmask[s] > 0) { gidx[cnt] = s; gvalid[cnt] = 1.f; cnt++; }
  for (int s = 0; s < S && cnt < NG; s++)
    if (gmask[s] == 0) { gidx[cnt] = s; gvalid[cnt] = 0.f; cnt++; }
}

// ---------------- embedding + LayerNorm (writes f32 + f16) ----------------
__global__ __launch_bounds__(256) void embed_ln_kernel(
    const int* __restrict__ ids, const float* __restrict__ tok,
    const float* __restrict__ pos, const float* __restrict__ g,
    const float* __restrict__ b, float* __restrict__ h, f16* __restrict__ h16) {
  int s = blockIdx.x, t = threadIdx.x;
  __shared__ float xs[HID];
  __shared__ float red[256];
  const float* tr = tok + (size_t)ids[s] * HID;
  const float* pr = pos + (size_t)s * HID;
  float ls = 0.f;
  for (int i = t; i < HID; i += 256) { float v = tr[i] + pr[i]; xs[i] = v; ls += v; }
  float mu = block_reduce_sum(ls, red) * (1.f / HID);
  float lv = 0.f;
  for (int i = t; i < HID; i += 256) { float d = xs[i] - mu; lv += d * d; }
  float var = block_reduce_sum(lv, red) * (1.f / HID);
  float inv = rsqrtf(var + 1e-5f);
  for (int i = t; i < HID; i += 256) {
    float o = (xs[i] - mu) * inv * g[i] + b[i];
    h[(size_t)s * HID + i] = o;
    h16[(size_t)s * HID + i] = (f16)o;
  }
}

// -------- residual add (f16 proj) + LayerNorm (in-place on h, also f16) --------
__global__ __launch_bounds__(256) void add_ln_kernel(
    float* __restrict__ h, const f16* __restrict__ x2,
    const float* __restrict__ g, const float* __restrict__ b, f16* __restrict__ h16) {
  int s = blockIdx.x, t = threadIdx.x;
  __shared__ float xs[HID];
  __shared__ float red[256];
  float ls = 0.f;
  for (int i = t; i < HID; i += 256) {
    float v = h[(size_t)s * HID + i] + (float)x2[(size_t)s * HID + i];
    xs[i] = v; ls += v;
  }
  float mu = block_reduce_sum(ls, red) * (1.f / HID);
  float lv = 0.f;
  for (int i = t; i < HID; i += 256) { float d = xs[i] - mu; lv += d * d; }
  float var = block_reduce_sum(lv, red) * (1.f / HID);
  float inv = rsqrtf(var + 1e-5f);
  for (int i = t; i < HID; i += 256) {
    float o = (xs[i] - mu) * inv * g[i] + b[i];
    h[(size_t)s * HID + i] = o;
    h16[(size_t)s * HID + i] = (f16)o;
  }
}

// ------ weight transpose + f16 convert, ALL layers: W[l][K][N] f32 -> WT[l][N][K] f16
__global__ __launch_bounds__(256) void wt_kernel(const float* __restrict__ W,
                                                 f16* __restrict__ WT, int K, int N) {
  size_t lo = (size_t)blockIdx.z * K * N;
  const float* Wl = W + lo;
  f16* WTl = WT + lo;
  __shared__ float tile[32][33];
  int k0 = blockIdx.y * 32, n0 = blockIdx.x * 32;
  int t = threadIdx.x;
  int r = t >> 3, c = (t & 7) * 4;
  float4 v = *(const float4*)&Wl[(size_t)(k0 + r) * N + n0 + c];
  tile[r][c] = v.x; tile[r][c + 1] = v.y; tile[r][c + 2] = v.z; tile[r][c + 3] = v.w;
  __syncthreads();
  int n = t >> 3, kq = (t & 7) * 4;
  f16x4 o = {(f16)tile[kq][n], (f16)tile[kq + 1][n], (f16)tile[kq + 2][n], (f16)tile[kq + 3][n]};
  *(f16x4*)&WTl[(size_t)(n0 + n) * K + k0 + kq] = o;
}

// ---- fp16 MFMA GEMM 128x128, single-buffer 2-barrier (proven structure) ----
#define GBK 64

template <int OMODE, bool GELU>  // OMODE 0: f32 out, 1: f16 out
__global__ __launch_bounds__(256) void gemm_f16_kernel(
    const f16* __restrict__ A, const f16* __restrict__ BT,
    const float* __restrict__ bias, void* __restrict__ Cout, int M, int N, int K) {
  __shared__ f16 As[128 * GBK];
  __shared__ f16 Bs[128 * GBK];
  int t = threadIdx.x, lane = t & 63, wave = t >> 6;
  int wr = wave >> 1, wc = wave & 1;
  int gx = gridDim.x;
  int nl = xcd_swz(blockIdx.y * gx + blockIdx.x, gx * gridDim.y);
  int bx = nl % gx, by = nl / gx;

  f32x4 acc[4][4];
#pragma unroll
  for (int mi = 0; mi < 4; mi++)
#pragma unroll
    for (int ni = 0; ni < 4; ni++) acc[mi][ni] = (f32x4){0.f, 0.f, 0.f, 0.f};

  const f16* Ablk = A + (size_t)(by * 128) * K;
  const f16* Bblk = BT + (size_t)(bx * 128) * K;
  int rl = lane >> 3;        // row within 8-row group
  int lc = (lane & 7) ^ rl;  // pre-swizzled source chunk (linear LDS dest)

  for (int k0 = 0; k0 < K; k0 += GBK) {
#pragma unroll
    for (int ii = 0; ii < 4; ii++) {
      int i = wave * 4 + ii;
      int r = i * 8 + rl;
      async16(&As[i * 512], Ablk + (size_t)r * K + k0 + lc * 8);
      async16(&Bs[i * 512], Bblk + (size_t)r * K + k0 + lc * 8);
    }
    __syncthreads();
#pragma unroll
    for (int kc = 0; kc < 2; kc++) {
      f16x8 af[4], bf[4];
#pragma unroll
      for (int mi = 0; mi < 4; mi++) {
        int row = wr * 64 + mi * 16 + (lane & 15);
        int pc = (kc * 4 + (lane >> 4)) ^ (row & 7);
        af[mi] = *(const f16x8*)&As[row * 64 + pc * 8];
      }
#pragma unroll
      for (int ni = 0; ni < 4; ni++) {
        int row = wc * 64 + ni * 16 + (lane & 15);
        int pc = (kc * 4 + (lane >> 4)) ^ (row & 7);
        bf[ni] = *(const f16x8*)&Bs[row * 64 + pc * 8];
      }
#pragma unroll
      for (int mi = 0; mi < 4; mi++)
#pragma unroll
        for (int ni = 0; ni < 4; ni++)
          acc[mi][ni] = __builtin_amdgcn_mfma_f32_16x16x32_f16(af[mi], bf[ni], acc[mi][ni], 0, 0, 0);
    }
    __syncthreads();
  }

  int row_base = by * 128 + wr * 64 + (lane >> 4) * 4;
  int col_base = bx * 128 + wc * 64 + (lane & 15);
#pragma unroll
  for (int mi = 0; mi < 4; mi++) {
#pragma unroll
    for (int ni = 0; ni < 4; ni++) {
      int col = col_base + ni * 16;
      float bs = bias[col];
#pragma unroll
      for (int j = 0; j < 4; j++) {
        int row = row_base + mi * 16 + j;
        float x = acc[mi][ni][j] + bs;
        if (GELU) x = 0.5f * x * (1.f + erff(x * 0.70710678118654752f));
        if (OMODE == 0) ((float*)Cout)[(size_t)row * N + col] = x;
        else ((f16*)Cout)[(size_t)row * N + col] = (f16)x;
      }
    }
  }
}

// ---- fp16 MFMA GEMM 128x64 (for N=768 outputs: grid 384 >= 256 CUs) ----
template <int OMODE, bool GELU>
__global__ __launch_bounds__(256) void gemm_f16_n64_kernel(
    const f16* __restrict__ A, const f16* __restrict__ BT,
    const float* __restrict__ bias, void* __restrict__ Cout, int M, int N, int K) {
  __shared__ f16 As[128 * GBK];  // 16 KB
  __shared__ f16 Bs[64 * GBK];   // 8 KB
  int t = threadIdx.x, lane = t & 63, wave = t >> 6;
  int wr = wave >> 1, wc = wave & 1;  // wr: 64-row half, wc: 32-col half
  int gx = gridDim.x;
  int nl = xcd_swz(blockIdx.y * gx + blockIdx.x, gx * gridDim.y);
  int bx = nl % gx, by = nl / gx;

  f32x4 acc[4][2];
#pragma unroll
  for (int mi = 0; mi < 4; mi++)
#pragma unroll
    for (int ni = 0; ni < 2; ni++) acc[mi][ni] = (f32x4){0.f, 0.f, 0.f, 0.f};

  const f16* Ablk = A + (size_t)(by * 128) * K;
  const f16* Bblk = BT + (size_t)(bx * 64) * K;
  int rl = lane >> 3;
  int lc = (lane & 7) ^ rl;

  for (int k0 = 0; k0 < K; k0 += GBK) {
#pragma unroll
    for (int ii = 0; ii < 4; ii++) {
      int i = wave * 4 + ii;
      int r = i * 8 + rl;
      async16(&As[i * 512], Ablk + (size_t)r * K + k0 + lc * 8);
    }
#pragma unroll
    for (int ii = 0; ii < 2; ii++) {
      int i = wave * 2 + ii;
      int r = i * 8 + rl;
      async16(&Bs[i * 512], Bblk + (size_t)r * K + k0 + lc * 8);
    }
    __syncthreads();
#pragma unroll
    for (int kc = 0; kc < 2; kc++) {
      f16x8 af[4], bf[2];
#pragma unroll
      for (int mi = 0; mi < 4; mi++) {
        int row = wr * 64 + mi * 16 + (lane & 15);
        int pc = (kc * 4 + (lane >> 4)) ^ (row & 7);
        af[mi] = *(const f16x8*)&As[row * 64 + pc * 8];
      }
#pragma unroll
      for (int ni = 0; ni < 2; ni++) {
        int row = wc * 32 + ni * 16 + (lane & 15);
        int pc = (kc * 4 + (lane >> 4)) ^ (row & 7);
        bf[ni] = *(const f16x8*)&Bs[row * 64 + pc * 8];
      }
#pragma unroll
      for (int mi = 0; mi < 4; mi++)
#pragma unroll
        for (int ni = 0; ni < 2; ni++)
          acc[mi][ni] = __builtin_amdgcn_mfma_f32_16x16x32_f16(af[mi], bf[ni], acc[mi][ni], 0, 0, 0);
    }
    __syncthreads();
  }

  int row_base = by * 128 + wr * 64 + (lane >> 4) * 4;
  int col_base = bx * 64 + wc * 32 + (lane & 15);
#pragma unroll
  for (int mi = 0; mi < 4; mi++) {
#pragma unroll
    for (int ni = 0; ni < 2; ni++) {
      int col = col_base + ni * 16;
      float bs = bias[col];
#pragma unroll
      for (int j = 0; j < 4; j++) {
        int row = row_base + mi * 16 + j;
        float x = acc[mi][ni][j] + bs;
        if (GELU) x = 0.5f * x * (1.f + erff(x * 0.70710678118654752f));
        if (OMODE == 0) ((float*)Cout)[(size_t)row * N + col] = x;
        else ((f16*)Cout)[(size_t)row * N + col] = (f16)x;
      }
    }
  }
}

// ---------------- MFMA local windowed attention ----------------
#define ROWP 72  // padded LDS row: 64 halves + 8 pad (144B) -> bank-spread

__global__ __launch_bounds__(256) void local_attn_mfma_kernel(
    const f16* __restrict__ qkv, const int* __restrict__ amask,
    const int* __restrict__ gmask, const int* __restrict__ gidx,
    const float* __restrict__ gvalid, f16* __restrict__ outp) {
  int nl = xcd_swz(blockIdx.x, NH * 64);
  int h = nl >> 6;
  int qb = nl & 63;
  int q0 = qb * 64;
  int t = threadIdx.x, lane = t & 63, w = t >> 6;
  int g4 = lane >> 4, l15 = lane & 15;

  __shared__ f16 Qs[64 * ROWP];
  __shared__ f16 Kt[64 * ROWP];      // [k][d]
  __shared__ f16 Vt[64 * ROWP];      // [d][k]  (transposed)
  __shared__ f16 Pb[4 * 16 * ROWP];  // per-wave P^ rows [q][k]
  __shared__ unsigned kokLo, kokHi;
  __shared__ float gvs[NG];

  {  // stage Q (scaled by 1/8)
    int r = t >> 2, c2 = (t & 3) * 2;
    const f16* qr = qkv + (size_t)(q0 + r) * QKV3 + h * DH + c2 * 8;
    f16x8 v0 = *(const f16x8*)qr;
    f16x8 v1 = *(const f16x8*)(qr + 8);
#pragma unroll
    for (int e = 0; e < 8; e++) { v0[e] = v0[e] * (f16)0.125f; v1[e] = v1[e] * (f16)0.125f; }
    *(f16x8*)&Qs[r * ROWP + c2 * 8] = v0;
    *(f16x8*)&Qs[r * ROWP + c2 * 8 + 8] = v1;
    if (t < NG) gvs[t] = gvalid[t];
  }
  __syncthreads();

  int qrow = w * 16 + l15;
  f16x8 qf0 = *(const f16x8*)&Qs[qrow * ROWP + g4 * 8];
  f16x8 qf1 = *(const f16x8*)&Qs[qrow * ROWP + 32 + g4 * 8];

  float mb = -50000.f, lp = 0.f;
  f32x4 oacc[4];
#pragma unroll
  for (int sd = 0; sd < 4; sd++) oacc[sd] = (f32x4){0.f, 0.f, 0.f, 0.f};

  f16* Pw = &Pb[w * 16 * ROWP];

  for (int kt = 0; kt <= 9; kt++) {
    int jb = q0 - 256 + kt * 64;
    bool isG = (kt == 9);
    if (!isG && (jb + 64 <= 0 || jb >= S)) continue;  // uniform across block
    __syncthreads();
    {  // stage K tile [k][d]
      int k = t >> 2, c2 = (t & 3) * 2;
      int j = isG ? (k < NG ? gidx[k] : -1) : (jb + k);
      bool jv = isG ? (k < NG && gvs[k] > 0.f) : (j >= 0 && j < S);
      f16x8 v0 = {}, v1 = {};
      if (jv) {
        const f16* kr = qkv + (size_t)j * QKV3 + HID + h * DH + c2 * 8;
        v0 = *(const f16x8*)kr; v1 = *(const f16x8*)(kr + 8);
      }
      *(f16x8*)&Kt[k * ROWP + c2 * 8] = v0;
      *(f16x8*)&Kt[k * ROWP + c2 * 8 + 8] = v1;
    }
    if (w == 0) {  // key-ok bitmask
      int k = lane;
      bool ok;
      if (isG) ok = (k < NG && gvs[k] > 0.f);
      else {
        int j = jb + k;
        ok = (j >= 0 && j < S) && (amask[j] != 0) && (gmask[j] == 0);
      }
      unsigned long long m = __ballot(ok);
      if (lane == 0) { kokLo = (unsigned)m; kokHi = (unsigned)(m >> 32); }
    }
    {  // stage V transposed [d][k], f16x2 writes
      int k2 = (t & 31) * 2, dq = (t >> 5) * 8;
      int j0 = isG ? (k2 < NG ? gidx[k2] : -1) : (jb + k2);
      int j1 = isG ? (k2 + 1 < NG ? gidx[k2 + 1] : -1) : (jb + k2 + 1);
      bool ok0 = isG ? (k2 < NG && gvs[k2] > 0.f) : (j0 >= 0 && j0 < S);
      bool ok1 = isG ? (k2 + 1 < NG && gvs[k2 + 1] > 0.f) : (j1 >= 0 && j1 < S);
      f16x8 va = {}, vb = {};
      if (ok0) va = *(const f16x8*)(qkv + (size_t)j0 * QKV3 + 2 * HID + h * DH + dq);
      if (ok1) vb = *(const f16x8*)(qkv + (size_t)j1 * QKV3 + 2 * HID + h * DH + dq);
#pragma unroll
      for (int e = 0; e < 8; e++) {
        f16x2 pr = {va[e], vb[e]};
        *(f16x2*)&Vt[(dq + e) * ROWP + k2] = pr;
      }
    }
    __syncthreads();

    unsigned long long kok = ((unsigned long long)kokHi << 32) | (unsigned long long)kokLo;

    // QK^T (swapped): S^T[k][q]
    f32x4 sv[4];
    __builtin_amdgcn_s_setprio(1);
#pragma unroll
    for (int s4 = 0; s4 < 4; s4++) {
      int krow = s4 * 16 + l15;
      f16x8 ka0 = *(const f16x8*)&Kt[krow * ROWP + g4 * 8];
      f16x8 ka1 = *(const f16x8*)&Kt[krow * ROWP + 32 + g4 * 8];
      f32x4 a = {0.f, 0.f, 0.f, 0.f};
      a = __builtin_amdgcn_mfma_f32_16x16x32_f16(ka0, qf0, a, 0, 0, 0);
      a = __builtin_amdgcn_mfma_f32_16x16x32_f16(ka1, qf1, a, 0, 0, 0);
      sv[s4] = a;
    }
    __builtin_amdgcn_s_setprio(0);
    int ql = w * 16 + l15;
#pragma unroll
    for (int s4 = 0; s4 < 4; s4++)
#pragma unroll
      for (int r = 0; r < 4; r++) {
        int kl = s4 * 16 + g4 * 4 + r;
        bool ok = (kok >> kl) & 1ull;
        if (kt == 0) ok = ok && (kl >= ql);
        else if (kt == 8) ok = ok && (kl <= ql);
        sv[s4][r] = ok ? sv[s4][r] : -1e30f;
      }
    // online softmax (per query column)
    float mt = -1e30f;
#pragma unroll
    for (int s4 = 0; s4 < 4; s4++)
#pragma unroll
      for (int r = 0; r < 4; r++) mt = fmaxf(mt, sv[s4][r]);
    mt = fmaxf(mt, __shfl_xor(mt, 16));
    mt = fmaxf(mt, __shfl_xor(mt, 32));
    float mn = fmaxf(mb, mt);
    float corr = __expf(mb - mn);
    mb = mn;
    lp *= corr;
#pragma unroll
    for (int sd = 0; sd < 4; sd++)
#pragma unroll
      for (int r = 0; r < 4; r++) oacc[sd][r] *= corr;
#pragma unroll
    for (int s4 = 0; s4 < 4; s4++) {
#pragma unroll
      for (int rp = 0; rp < 2; rp++) {
        float p0 = __expf(sv[s4][rp * 2] - mn);
        float p1 = __expf(sv[s4][rp * 2 + 1] - mn);
        f16 h0 = (f16)p0, h1 = (f16)p1;
        lp += (float)h0 + (float)h1;
        int kl = s4 * 16 + g4 * 4 + rp * 2;
        f16x2 pr = {h0, h1};
        *(f16x2*)&Pw[l15 * ROWP + kl] = pr;
      }
    }
    // PV: O^T[d][q] += V^T @ P^T
    f16x8 pf0 = *(const f16x8*)&Pw[l15 * ROWP + g4 * 8];
    f16x8 pf1 = *(const f16x8*)&Pw[l15 * ROWP + 32 + g4 * 8];
    __builtin_amdgcn_s_setprio(1);
#pragma unroll
    for (int sd = 0; sd < 4; sd++) {
      int drow = sd * 16 + l15;
      f16x8 va0 = *(const f16x8*)&Vt[drow * ROWP + g4 * 8];
      f16x8 va1 = *(const f16x8*)&Vt[drow * ROWP + 32 + g4 * 8];
      oacc[sd] = __builtin_amdgcn_mfma_f32_16x16x32_f16(va0, pf0, oacc[sd], 0, 0, 0);
      oacc[sd] = __builtin_amdgcn_mfma_f32_16x16x32_f16(va1, pf1, oacc[sd], 0, 0, 0);
    }
    __builtin_amdgcn_s_setprio(0);
  }

  float lt = lp + __shfl_xor(lp, 16);
  lt = lt + __shfl_xor(lt, 32);
  float inv = (lt > 0.f) ? 1.f / lt : 0.f;
  int qg = q0 + w * 16 + l15;
  f16* orow = outp + (size_t)qg * HID + h * DH;
#pragma unroll
  for (int sd = 0; sd < 4; sd++)
#pragma unroll
    for (int r = 0; r < 4; r++)
      orow[sd * 16 + g4 * 4 + r] = (f16)(oacc[sd][r] * inv);
}

// ============ global-token attention, split-K pipeline (3 kernels) ============
// GA1: scores + per-chunk (max, sumexp) stats. grid = NH*16.
__global__ __launch_bounds__(256) void gscore_kernel(
    const f16* __restrict__ qkv, const int* __restrict__ amask,
    const int* __restrict__ gidx, float* __restrict__ Sg, float2* __restrict__ cstat) {
  int h = blockIdx.x >> 4, jc = blockIdx.x & 15;
  int t = threadIdx.x, lane = t & 63, w = t >> 6;
  __shared__ f16 Qs[NG][DH];
  __shared__ float wred[4][NG];
  __shared__ float cmaxs[NG];
  if (t < 128) {
    int g = t >> 3, c = (t & 7) * 8;
    const f16* qr = qkv + (size_t)gidx[g] * QKV3 + h * DH + c;
    *(f16x8*)&Qs[g][c] = *(const f16x8*)qr;
  }
  __syncthreads();
  int j = jc * 256 + t;
  const f16x8* kr = (const f16x8*)(qkv + (size_t)j * QKV3 + HID + h * DH);
  f16x8 kv[8];
#pragma unroll
  for (int c = 0; c < 8; c++) kv[c] = kr[c];
  bool ok = amask[j] != 0;
  float sg[NG];
#pragma unroll 4
  for (int g = 0; g < NG; g++) {
    float s = 0.f;
#pragma unroll
    for (int c = 0; c < 8; c++) {
      f16x8 qv = *(const f16x8*)&Qs[g][c * 8];
#pragma unroll
      for (int e = 0; e < 8; e++) s += (float)qv[e] * (float)kv[c][e];
    }
    sg[g] = ok ? s * 0.125f : NEGV;
    Sg[(size_t)(h * NG + g) * S + j] = sg[g];
  }
  // per-chunk max (wave reduce -> cross-wave)
#pragma unroll
  for (int g = 0; g < NG; g++) {
    float m = sg[g];
#pragma unroll
    for (int st = 1; st < 64; st <<= 1) m = fmaxf(m, __shfl_xor(m, st));
    if (lane == 0) wred[w][g] = m;
  }
  __syncthreads();
  if (t < NG)
    cmaxs[t] = fmaxf(fmaxf(wred[0][t], wred[1][t]), fmaxf(wred[2][t], wred[3][t]));
  __syncthreads();
  // per-chunk sumexp
#pragma unroll
  for (int g = 0; g < NG; g++) {
    float p = __expf(sg[g] - cmaxs[g]);
#pragma unroll
    for (int st = 1; st < 64; st <<= 1) p += __shfl_xor(p, st);
    if (lane == 0) wred[w][g] = p;
  }
  __syncthreads();
  if (t < NG) {
    float s4 = wred[0][t] + wred[1][t] + wred[2][t] + wred[3][t];
    cstat[((size_t)(h * NG + t)) * 16 + jc] = make_float2(cmaxs[t], s4);
  }
}

// GA2: PV split-K partials (combines chunk stats internally). grid = NH*16.
__global__ __launch_bounds__(256) void gpv_kernel(
    const f16* __restrict__ qkv, const float* __restrict__ Sg,
    const float2* __restrict__ cstat, float* __restrict__ part) {
  int h = blockIdx.x >> 4, jc = blockIdx.x & 15;
  int jb = jc * 256;
  int t = threadIdx.x;
  __shared__ float Ps[NG][256];
  __shared__ f16 Vs[256][DH];
  __shared__ float ms[NG], dinv[NG];
  if (t < NG) {
    const float2* cs = &cstat[((size_t)(h * NG + t)) * 16];
    float m = -1e30f;
#pragma unroll
    for (int c = 0; c < 16; c++) m = fmaxf(m, cs[c].x);
    float den = 0.f;
#pragma unroll
    for (int c = 0; c < 16; c++) den += cs[c].y * __expf(cs[c].x - m);
    ms[t] = m;
    dinv[t] = den > 0.f ? 1.f / den : 0.f;
  }
  __syncthreads();
#pragma unroll
  for (int g = 0; g < NG; g++)
    Ps[g][t] = __expf(Sg[(size_t)(h * NG + g) * S + jb + t] - ms[g]) * dinv[g];
  {
    int r = t >> 3, c = (t & 7) * 8;
#pragma unroll
    for (int pp = 0; pp < 8; pp++) {
      int row = pp * 32 + r;
      const f16* vr = qkv + (size_t)(jb + row) * QKV3 + 2 * HID + h * DH + c;
      *(f16x8*)&Vs[row][c] = *(const f16x8*)vr;
    }
  }
  __syncthreads();
  int d = t & 63, g4 = t >> 6;
  float o0 = 0.f, o1 = 0.f, o2 = 0.f, o3 = 0.f;
#pragma unroll 8
  for (int j = 0; j < 256; j++) {
    float v = (float)Vs[j][d];
    o0 += Ps[g4][j] * v;
    o1 += Ps[g4 + 4][j] * v;
    o2 += Ps[g4 + 8][j] * v;
    o3 += Ps[g4 + 12][j] * v;
  }
  size_t base = ((size_t)h * NG) * 16 * 64;
  part[base + ((size_t)(g4) * 16 + jc) * 64 + d] = o0;
  part[base + ((size_t)(g4 + 4) * 16 + jc) * 64 + d] = o1;
  part[base + ((size_t)(g4 + 8) * 16 + jc) * 64 + d] = o2;
  part[base + ((size_t)(g4 + 12) * 16 + jc) * 64 + d] = o3;
}

// GA3: reduce partials, overwrite valid global rows. grid = NH*NG, 64 threads.
__global__ __launch_bounds__(64) void gout_kernel(
    const float* __restrict__ part, const int* __restrict__ gidx,
    const float* __restrict__ gvalid, f16* __restrict__ attn16) {
  int h = blockIdx.x >> 4, g = blockIdx.x & 15;
  if (gvalid[g] <= 0.f) return;
  int d = threadIdx.x;
  const float* pr = part + (((size_t)(h * NG + g)) * 16) * 64 + d;
  float s = 0.f;
#pragma unroll
  for (int jc = 0; jc < 16; jc++) s += pr[jc * 64];
  attn16[(size_t)gidx[g] * HID + h * DH + d] = (f16)s;
}

// ---------------- masked mean pool (partials) + classifier head ----------------
__global__ __launch_bounds__(256) void pool_part_kernel(
    const float* __restrict__ h, const int* __restrict__ amask, float* __restrict__ part) {
  int b = blockIdx.x, t = threadIdx.x;
  float a0 = 0.f, a1 = 0.f, a2 = 0.f;
  for (int r = 0; r < 64; r++) {
    int s = b * 64 + r;
    float w = (float)amask[s];
    const float* hr = h + (size_t)s * HID;
    a0 += hr[t] * w;
    a1 += hr[t + 256] * w;
    a2 += hr[t + 512] * w;
  }
  part[(size_t)b * HID + t] = a0;
  part[(size_t)b * HID + t + 256] = a1;
  part[(size_t)b * HID + t + 512] = a2;
}

__global__ __launch_bounds__(256) void cls_head_kernel(
    const float* __restrict__ part, const int* __restrict__ amask,
    const float* __restrict__ clsW, const float* __restrict__ clsb,
    float* __restrict__ out) {
  __shared__ float pooled[HID];
  __shared__ float red[256];
  int t = threadIdx.x;
  for (int i = t; i < HID; i += 256) {
    float s = 0.f;
    for (int b2 = 0; b2 < 64; b2++) s += part[(size_t)b2 * HID + i];
    pooled[i] = s;
  }
  float c = 0.f;
  for (int s2 = t; s2 < S; s2 += 256) c += (float)amask[s2];
  float cnt = block_reduce_sum(c, red);
  float p0 = 0.f, p1 = 0.f;
  for (int i = t; i < HID; i += 256) {
    float pv = pooled[i] / cnt;
    p0 += pv * clsW[i * 2];
    p1 += pv * clsW[i * 2 + 1];
  }
  float s0 = block_reduce_sum(p0, red);
  float s1 = block_reduce_sum(p1, red);
  if (t == 0) { out[0] = s0 + clsb[0]; out[1] = s1 + clsb[1]; }
}

// ---------------- launch ----------------
extern "C" void kernel_launch(void* const* d_in, const int* in_sizes, int n_in,
                              void* d_out, int out_size, void* d_ws, size_t ws_size,
                              hipStream_t stream) {
  const int* ids = (const int*)d_in[0];
  const int* amask = (const int*)d_in[1];
  const int* gmask = (const int*)d_in[2];
  const float* tok = (const float*)d_in[3];
  const float* pos = (const float*)d_in[4];
  const float* elnw = (const float*)d_in[5];
  const float* elnb = (const float*)d_in[6];
  const float* Wqkv = (const float*)d_in[7];
  const float* bqkv = (const float*)d_in[8];
  const float* Wo = (const float*)d_in[9];
  const float* bo = (const float*)d_in[10];
  const float* ln1w = (const float*)d_in[11];
  const float* ln1b = (const float*)d_in[12];
  const float* W1 = (const float*)d_in[13];
  const float* b1 = (const float*)d_in[14];
  const float* W2 = (const float*)d_in[15];
  const float* b2 = (const float*)d_in[16];
  const float* ln2w = (const float*)d_in[17];
  const float* ln2b = (const float*)d_in[18];
  const float* clsW = (const float*)d_in[19];
  const float* clsb = (const float*)d_in[20];

  char* w8 = (char*)d_ws;
  size_t o = 0;
  float* h = (float*)(w8 + o); o += (size_t)S * HID * 4;
  f16* h16 = (f16*)(w8 + o); o += (size_t)S * HID * 2;
  f16* qkv16 = (f16*)(w8 + o); o += (size_t)S * QKV3 * 2;
  f16* attn16 = (f16*)(w8 + o); o += (size_t)S * HID * 2;
  f16* ff16 = (f16*)(w8 + o); o += (size_t)S * FF * 2;
  f16* proj16 = (f16*)(w8 + o); o += (size_t)S * HID * 2;
  float* part = (float*)(w8 + o); o += (size_t)64 * HID * 4;
  int* gidx = (int*)(w8 + o); o += 64;
  float* gvalid = (float*)(w8 + o); o += 64;
  f16* WqkvT = (f16*)(w8 + o); o += (size_t)NLAYER * HID * QKV3 * 2;
  f16* WoT = (f16*)(w8 + o); o += (size_t)NLAYER * HID * HID * 2;
  f16* W1T = (f16*)(w8 + o); o += (size_t)NLAYER * HID * FF * 2;
  f16* W2T = (f16*)(w8 + o); o += (size_t)NLAYER * FF * HID * 2;
  float* Sg = (float*)(w8 + o); o += (size_t)NH * NG * S * 4;
  float2* cstat = (float2*)(w8 + o); o += (size_t)NH * NG * 16 * 8;
  float* gpart = (float*)(w8 + o); o += (size_t)NH * NG * 16 * 64 * 4;

  gidx_kernel<<<1, 64, 0, stream>>>(gmask, gidx, gvalid);
  embed_ln_kernel<<<S, 256, 0, stream>>>(ids, tok, pos, elnw, elnb, h, h16);
  wt_kernel<<<dim3(QKV3 / 32, HID / 32, NLAYER), 256, 0, stream>>>(Wqkv, WqkvT, HID, QKV3);
  wt_kernel<<<dim3(HID / 32, HID / 32, NLAYER), 256, 0, stream>>>(Wo, WoT, HID, HID);
  wt_kernel<<<dim3(FF / 32, HID / 32, NLAYER), 256, 0, stream>>>(W1, W1T, HID, FF);
  wt_kernel<<<dim3(HID / 32, FF / 32, NLAYER), 256, 0, stream>>>(W2, W2T, FF, HID);

  for (int l = 0; l < NLAYER; l++) {
    gemm_f16_kernel<1, false><<<dim3(QKV3 / 128, S / 128), 256, 0, stream>>>(
        h16, WqkvT + (size_t)l * HID * QKV3, bqkv + (size_t)l * QKV3, qkv16, S, QKV3, HID);
    local_attn_mfma_kernel<<<NH * 64, 256, 0, stream>>>(
        qkv16, amask, gmask, gidx, gvalid, attn16);
    gscore_kernel<<<NH * 16, 256, 0, stream>>>(qkv16, amask, gidx, Sg, cstat);
    gpv_kernel<<<NH * 16, 256, 0, stream>>>(qkv16, Sg, cstat, gpart);
    gout_kernel<<<NH * NG, 64, 0, stream>>>(gpart, gidx, gvalid, attn16);
    gemm_f16_n64_kernel<1, false><<<dim3(HID / 64, S / 128), 256, 0, stream>>>(
        attn16, WoT + (size_t)l * HID * HID, bo + (size_t)l * HID, proj16, S, HID, HID);
    add_ln_kernel<<<S, 256, 0, stream>>>(h, proj16, ln1w + (size_t)l * HID,
                                         ln1b + (size_t)l * HID, h16);
    gemm_f16_kernel<1, true><<<dim3(FF / 128, S / 128), 256, 0, stream>>>(
        h16, W1T + (size_t)l * HID * FF, b1 + (size_t)l * FF, ff16, S, FF, HID);
    gemm_f16_n64_kernel<1, false><<<dim3(HID / 64, S / 128), 256, 0, stream>>>(
        ff16, W2T + (size_t)l * FF * HID, b2 + (size_t)l * HID, proj16, S, HID, FF);
    add_ln_kernel<<<S, 256, 0, stream>>>(h, proj16, ln2w + (size_t)l * HID,
                                         ln2b + (size_t)l * HID, h16);
  }
  pool_part_kernel<<<64, 256, 0, stream>>>(h, amask, part);
  cls_head_kernel<<<1, 256, 0, stream>>>(part, amask, clsW, clsb, (float*)d_out);
}